// Round 1
// baseline (1706.696 us; speedup 1.0000x reference)
//
#include <hip/hip_runtime.h>
#include <math.h>

#define B_   4
#define L_   1024
#define DM   1024
#define DE   2048
#define NS   16
#define RK   64
#define M_   (B_*L_)   // 4096

// ---------------------------------------------------------------------------
// C[M,N] = A[M,K] @ Bw[N,K]^T   (A row-major lda, Bw row-major ldb, C ldc)
// 128x128 tile, BK=8, 256 threads, 8x8 per thread. M,N multiples of 128, K of 8.
// ---------------------------------------------------------------------------
__global__ __launch_bounds__(256)
void gemm_abt_128(const float* __restrict__ A, int lda,
                  const float* __restrict__ Bw, int ldb,
                  float* __restrict__ C, int ldc, int K) {
  __shared__ float As[8][128];
  __shared__ float Bs[8][128];
  const int tid = threadIdx.x;
  const int row0 = blockIdx.y * 128, col0 = blockIdx.x * 128;
  const int ty8 = (tid >> 4) * 8, tx8 = (tid & 15) * 8;
  const int r = tid >> 1, c4 = (tid & 1) * 4;
  const float* Ap = A + (size_t)(row0 + r) * lda + c4;
  const float* Bp = Bw + (size_t)(col0 + r) * ldb + c4;

  float acc[8][8];
  #pragma unroll
  for (int i = 0; i < 8; ++i)
    #pragma unroll
    for (int j = 0; j < 8; ++j) acc[i][j] = 0.f;

  float4 av = *(const float4*)Ap;
  float4 bv = *(const float4*)Bp;
  for (int k0 = 0; k0 < K; k0 += 8) {
    __syncthreads();
    As[c4+0][r] = av.x; As[c4+1][r] = av.y; As[c4+2][r] = av.z; As[c4+3][r] = av.w;
    Bs[c4+0][r] = bv.x; Bs[c4+1][r] = bv.y; Bs[c4+2][r] = bv.z; Bs[c4+3][r] = bv.w;
    __syncthreads();
    if (k0 + 8 < K) {                    // prefetch next tile while computing
      av = *(const float4*)(Ap + k0 + 8);
      bv = *(const float4*)(Bp + k0 + 8);
    }
    #pragma unroll
    for (int k = 0; k < 8; ++k) {
      const float4 a0 = *(const float4*)&As[k][ty8];
      const float4 a1 = *(const float4*)&As[k][ty8+4];
      const float4 b0 = *(const float4*)&Bs[k][tx8];
      const float4 b1 = *(const float4*)&Bs[k][tx8+4];
      const float a[8] = {a0.x,a0.y,a0.z,a0.w,a1.x,a1.y,a1.z,a1.w};
      const float b[8] = {b0.x,b0.y,b0.z,b0.w,b1.x,b1.y,b1.z,b1.w};
      #pragma unroll
      for (int i = 0; i < 8; ++i)
        #pragma unroll
        for (int j = 0; j < 8; ++j)
          acc[i][j] = fmaf(a[i], b[j], acc[i][j]);
    }
  }
  #pragma unroll
  for (int i = 0; i < 8; ++i) {
    float* Cp = C + (size_t)(row0 + ty8 + i) * ldc + col0 + tx8;
    *(float4*)Cp     = make_float4(acc[i][0],acc[i][1],acc[i][2],acc[i][3]);
    *(float4*)(Cp+4) = make_float4(acc[i][4],acc[i][5],acc[i][6],acc[i][7]);
  }
}

// ---------------------------------------------------------------------------
// Depthwise conv(k=3, pad 1) + bias + SiLU.  u = xz[:, :2048] (row stride 4096)
// ---------------------------------------------------------------------------
__global__ __launch_bounds__(256)
void conv_silu_k(const float* __restrict__ xz, const float* __restrict__ cw,
                 const float* __restrict__ cb, float* __restrict__ uc) {
  const int g = blockIdx.x * 256 + threadIdx.x;   // [0, M_*DE/4)
  const int m = g >> 9;                            // DE/4 = 512 float4 per row
  const int d4 = (g & 511) << 2;
  const int l = m & (L_ - 1);
  const float* row = xz + (size_t)m * 4096 + d4;
  float4 cur = *(const float4*)row;
  float4 prv = make_float4(0.f,0.f,0.f,0.f);
  float4 nxt = make_float4(0.f,0.f,0.f,0.f);
  if (l > 0)      prv = *(const float4*)(row - 4096);
  if (l < L_ - 1) nxt = *(const float4*)(row + 4096);
  const float pc[4] = {prv.x,prv.y,prv.z,prv.w};
  const float cc[4] = {cur.x,cur.y,cur.z,cur.w};
  const float nc[4] = {nxt.x,nxt.y,nxt.z,nxt.w};
  float o[4];
  #pragma unroll
  for (int i = 0; i < 4; ++i) {
    const int d = d4 + i;
    float v = cb[d] + cw[d*3]*pc[i] + cw[d*3+1]*cc[i] + cw[d*3+2]*nc[i];
    o[i] = v / (1.f + expf(-v));                  // SiLU
  }
  *(float4*)(uc + (size_t)m * DE + d4) = make_float4(o[0],o[1],o[2],o[3]);
}

// ---------------------------------------------------------------------------
// proj[M,96] = uc[M,2048] @ W_xproj[96,2048]^T.  BM=32, BN=96, BK=64.
// ---------------------------------------------------------------------------
__global__ __launch_bounds__(256)
void proj_k(const float* __restrict__ uc, const float* __restrict__ Wx,
            float* __restrict__ proj) {
  __shared__ float As[64][32];
  __shared__ float Bs[64][96];
  const int tid = threadIdx.x;
  const int row0 = blockIdx.x * 32;
  const int ty = tid >> 4, tx = tid & 15;   // ty: 2 rows each, tx: 6 cols each
  float acc[2][6];
  #pragma unroll
  for (int i = 0; i < 2; ++i)
    #pragma unroll
    for (int j = 0; j < 6; ++j) acc[i][j] = 0.f;

  for (int k0 = 0; k0 < DE; k0 += 64) {
    __syncthreads();
    #pragma unroll
    for (int q = 0; q < 2; ++q) {           // A tile: 32x64 = 512 float4
      const int f = q*256 + tid;
      const int rr = f >> 4, cc = (f & 15) << 2;
      float4 v = *(const float4*)(uc + (size_t)(row0+rr)*DE + k0 + cc);
      As[cc+0][rr]=v.x; As[cc+1][rr]=v.y; As[cc+2][rr]=v.z; As[cc+3][rr]=v.w;
    }
    #pragma unroll
    for (int q = 0; q < 6; ++q) {           // B tile: 96x64 = 1536 float4
      const int f = q*256 + tid;
      const int rr = f >> 4, cc = (f & 15) << 2;
      float4 v = *(const float4*)(Wx + (size_t)rr*DE + k0 + cc);
      Bs[cc+0][rr]=v.x; Bs[cc+1][rr]=v.y; Bs[cc+2][rr]=v.z; Bs[cc+3][rr]=v.w;
    }
    __syncthreads();
    #pragma unroll 8
    for (int k = 0; k < 64; ++k) {
      const float a0 = As[k][ty*2], a1 = As[k][ty*2+1];
      float b[6];
      #pragma unroll
      for (int j = 0; j < 6; ++j) b[j] = Bs[k][tx*6+j];
      #pragma unroll
      for (int j = 0; j < 6; ++j) {
        acc[0][j] = fmaf(a0, b[j], acc[0][j]);
        acc[1][j] = fmaf(a1, b[j], acc[1][j]);
      }
    }
  }
  #pragma unroll
  for (int i = 0; i < 2; ++i)
    #pragma unroll
    for (int j = 0; j < 6; ++j)
      proj[(size_t)(row0 + ty*2 + i)*96 + tx*6 + j] = acc[i][j];
}

// ---------------------------------------------------------------------------
// delta[M,2048] = softplus(dt[M,64] @ W_dt[2048,64]^T + b_dt). Single K pass.
// ---------------------------------------------------------------------------
__global__ __launch_bounds__(256)
void delta_k(const float* __restrict__ proj, const float* __restrict__ Wdt,
             const float* __restrict__ bdt, float* __restrict__ dl) {
  __shared__ float As[64][64];
  __shared__ float Bs[64][64];
  const int tid = threadIdx.x;
  const int row0 = blockIdx.y * 64, col0 = blockIdx.x * 64;
  const int ty = tid >> 4, tx = tid & 15;
  #pragma unroll
  for (int q = 0; q < 4; ++q) {             // each tile: 64x64 = 1024 float4
    const int f = q*256 + tid;
    const int rr = f >> 4, cc = (f & 15) << 2;
    float4 v = *(const float4*)(proj + (size_t)(row0+rr)*96 + 32 + cc);
    As[cc+0][rr]=v.x; As[cc+1][rr]=v.y; As[cc+2][rr]=v.z; As[cc+3][rr]=v.w;
    float4 w = *(const float4*)(Wdt + (size_t)(col0+rr)*64 + cc);
    Bs[cc+0][rr]=w.x; Bs[cc+1][rr]=w.y; Bs[cc+2][rr]=w.z; Bs[cc+3][rr]=w.w;
  }
  __syncthreads();
  float acc[4][4];
  #pragma unroll
  for (int i = 0; i < 4; ++i)
    #pragma unroll
    for (int j = 0; j < 4; ++j) acc[i][j] = 0.f;
  #pragma unroll 8
  for (int k = 0; k < 64; ++k) {
    const float4 a = *(const float4*)&As[k][ty*4];
    const float4 w = *(const float4*)&Bs[k][tx*4];
    const float a_[4]={a.x,a.y,a.z,a.w}, b_[4]={w.x,w.y,w.z,w.w};
    #pragma unroll
    for (int i = 0; i < 4; ++i)
      #pragma unroll
      for (int j = 0; j < 4; ++j)
        acc[i][j] = fmaf(a_[i], b_[j], acc[i][j]);
  }
  #pragma unroll
  for (int i = 0; i < 4; ++i) {
    const int m = row0 + ty*4 + i;
    #pragma unroll
    for (int j = 0; j < 4; ++j) {
      const int d = col0 + tx*4 + j;
      float v = acc[i][j] + bdt[d];
      float sp = (v > 20.f) ? v : log1pf(expf(v));
      dl[(size_t)m*DE + d] = sp;
    }
  }
}

// ---------------------------------------------------------------------------
// Selective scan. One thread per (b,d,n). 16-lane shuffle reduce for y_t.
// Writes final activation y = (y_ssm + uc*D)*silu(z) into xz[:, :2048] (dead u).
// ---------------------------------------------------------------------------
__global__ __launch_bounds__(256)
void scan_k(const float* __restrict__ dl, const float* __restrict__ uc,
            const float* __restrict__ proj, float* __restrict__ xz,
            const float* __restrict__ Alog, const float* __restrict__ Dv) {
  const int tid = threadIdx.x;
  const int bb = blockIdx.x;                 // 512 blocks: b = bb>>7, 16 d each
  const int b = bb >> 7;
  const int d = ((bb & 127) << 4) + (tid >> 4);
  const int n = tid & 15;
  const float An = -expf(Alog[d*NS + n]);
  const float Dd = Dv[d];
  float h = 0.f;
  const size_t base = (size_t)b * L_;
  for (int t = 0; t < L_; ++t) {
    const size_t mt = base + t;
    const float dv = dl[mt*DE + d];
    const float uv = uc[mt*DE + d];
    const float Bn = proj[mt*96 + n];
    const float Cn = proj[mt*96 + 16 + n];
    const float da = expf(dv * An);
    h = fmaf(da, h, dv * uv * Bn);
    float p = h * Cn;
    p += __shfl_xor(p, 1);
    p += __shfl_xor(p, 2);
    p += __shfl_xor(p, 4);
    p += __shfl_xor(p, 8);
    if (n == 0) {
      const float zv = xz[mt*4096 + 2048 + d];
      const float sz = zv / (1.f + expf(-zv));
      xz[mt*4096 + d] = (p + uv * Dd) * sz;
    }
  }
}

// ---------------------------------------------------------------------------
extern "C" void kernel_launch(void* const* d_in, const int* in_sizes, int n_in,
                              void* d_out, int out_size, void* d_ws, size_t ws_size,
                              hipStream_t stream) {
  const float* x    = (const float*)d_in[0];
  const float* Win  = (const float*)d_in[1];
  const float* cw   = (const float*)d_in[2];
  const float* cb   = (const float*)d_in[3];
  const float* Wx   = (const float*)d_in[4];
  const float* Wdt  = (const float*)d_in[5];
  const float* bdt  = (const float*)d_in[6];
  const float* Alog = (const float*)d_in[7];
  const float* Dv   = (const float*)d_in[8];
  const float* Wout = (const float*)d_in[9];
  float* out = (float*)d_out;
  float* ws  = (float*)d_ws;

  float* xz   = ws;                              // 4096*4096 f32 (u | z), y over u
  float* uc   = ws + 16777216;                   // 4096*2048
  float* proj = ws + 16777216 + 8388608;         // 4096*96
  float* dl   = proj + 393216;                   // 4096*2048

  // 1) xz = x @ W_in^T
  gemm_abt_128<<<dim3(32, 32), 256, 0, stream>>>(x, DM, Win, DM, xz, 4096, DM);
  // 2) uc = silu(depthwise_conv3(u) + conv_b)
  conv_silu_k<<<8192, 256, 0, stream>>>(xz, cw, cb, uc);
  // 3) proj = uc @ W_xproj^T
  proj_k<<<128, 256, 0, stream>>>(uc, Wx, proj);
  // 4) delta = softplus(dt @ W_dt^T + b_dt)
  delta_k<<<dim3(32, 64), 256, 0, stream>>>(proj, Wdt, bdt, dl);
  // 5) selective scan -> y (into xz[:, :2048])
  scan_k<<<512, 256, 0, stream>>>(dl, uc, proj, xz, Alog, Dv);
  // 6) out = y @ W_out^T
  gemm_abt_128<<<dim3(8, 32), 256, 0, stream>>>(xz, 4096, Wout, DE, out, DM, DE);
}

// Round 2
// 965.214 us; speedup vs baseline: 1.7682x; 1.7682x over previous
//
#include <hip/hip_runtime.h>
#include <math.h>

#define B_   4
#define L_   1024
#define DM   1024
#define DE   2048
#define NS   16
#define RK   64
#define M_   (B_*L_)   // 4096
#define NC   32        // scan chunks
#define CL   32        // chunk length (NC*CL == L_)

// ---------------------------------------------------------------------------
// C[M,N] = A[M,K] @ Bw[N,K]^T   (A row-major lda, Bw row-major ldb, C ldc)
// 128x128 tile, BK=8, 256 threads, 8x8 per thread. M,N multiples of 128, K of 8.
// ---------------------------------------------------------------------------
__global__ __launch_bounds__(256)
void gemm_abt_128(const float* __restrict__ A, int lda,
                  const float* __restrict__ Bw, int ldb,
                  float* __restrict__ C, int ldc, int K) {
  __shared__ float As[8][128];
  __shared__ float Bs[8][128];
  const int tid = threadIdx.x;
  const int row0 = blockIdx.y * 128, col0 = blockIdx.x * 128;
  const int ty8 = (tid >> 4) * 8, tx8 = (tid & 15) * 8;
  const int r = tid >> 1, c4 = (tid & 1) * 4;
  const float* Ap = A + (size_t)(row0 + r) * lda + c4;
  const float* Bp = Bw + (size_t)(col0 + r) * ldb + c4;

  float acc[8][8];
  #pragma unroll
  for (int i = 0; i < 8; ++i)
    #pragma unroll
    for (int j = 0; j < 8; ++j) acc[i][j] = 0.f;

  float4 av = *(const float4*)Ap;
  float4 bv = *(const float4*)Bp;
  for (int k0 = 0; k0 < K; k0 += 8) {
    __syncthreads();
    As[c4+0][r] = av.x; As[c4+1][r] = av.y; As[c4+2][r] = av.z; As[c4+3][r] = av.w;
    Bs[c4+0][r] = bv.x; Bs[c4+1][r] = bv.y; Bs[c4+2][r] = bv.z; Bs[c4+3][r] = bv.w;
    __syncthreads();
    if (k0 + 8 < K) {                    // prefetch next tile while computing
      av = *(const float4*)(Ap + k0 + 8);
      bv = *(const float4*)(Bp + k0 + 8);
    }
    #pragma unroll
    for (int k = 0; k < 8; ++k) {
      const float4 a0 = *(const float4*)&As[k][ty8];
      const float4 a1 = *(const float4*)&As[k][ty8+4];
      const float4 b0 = *(const float4*)&Bs[k][tx8];
      const float4 b1 = *(const float4*)&Bs[k][tx8+4];
      const float a[8] = {a0.x,a0.y,a0.z,a0.w,a1.x,a1.y,a1.z,a1.w};
      const float b[8] = {b0.x,b0.y,b0.z,b0.w,b1.x,b1.y,b1.z,b1.w};
      #pragma unroll
      for (int i = 0; i < 8; ++i)
        #pragma unroll
        for (int j = 0; j < 8; ++j)
          acc[i][j] = fmaf(a[i], b[j], acc[i][j]);
    }
  }
  #pragma unroll
  for (int i = 0; i < 8; ++i) {
    float* Cp = C + (size_t)(row0 + ty8 + i) * ldc + col0 + tx8;
    *(float4*)Cp     = make_float4(acc[i][0],acc[i][1],acc[i][2],acc[i][3]);
    *(float4*)(Cp+4) = make_float4(acc[i][4],acc[i][5],acc[i][6],acc[i][7]);
  }
}

// ---------------------------------------------------------------------------
// Depthwise conv(k=3, pad 1) + bias + SiLU.  u = xz[:, :2048] (row stride 4096)
// ---------------------------------------------------------------------------
__global__ __launch_bounds__(256)
void conv_silu_k(const float* __restrict__ xz, const float* __restrict__ cw,
                 const float* __restrict__ cb, float* __restrict__ uc) {
  const int g = blockIdx.x * 256 + threadIdx.x;   // [0, M_*DE/4)
  const int m = g >> 9;                            // DE/4 = 512 float4 per row
  const int d4 = (g & 511) << 2;
  const int l = m & (L_ - 1);
  const float* row = xz + (size_t)m * 4096 + d4;
  float4 cur = *(const float4*)row;
  float4 prv = make_float4(0.f,0.f,0.f,0.f);
  float4 nxt = make_float4(0.f,0.f,0.f,0.f);
  if (l > 0)      prv = *(const float4*)(row - 4096);
  if (l < L_ - 1) nxt = *(const float4*)(row + 4096);
  const float pc[4] = {prv.x,prv.y,prv.z,prv.w};
  const float cc[4] = {cur.x,cur.y,cur.z,cur.w};
  const float nc[4] = {nxt.x,nxt.y,nxt.z,nxt.w};
  float o[4];
  #pragma unroll
  for (int i = 0; i < 4; ++i) {
    const int d = d4 + i;
    float v = cb[d] + cw[d*3]*pc[i] + cw[d*3+1]*cc[i] + cw[d*3+2]*nc[i];
    o[i] = v / (1.f + __expf(-v));                // SiLU
  }
  *(float4*)(uc + (size_t)m * DE + d4) = make_float4(o[0],o[1],o[2],o[3]);
}

// ---------------------------------------------------------------------------
// proj[M,96] = uc[M,2048] @ W_xproj[96,2048]^T.  BM=32, BN=96, BK=64.
// ---------------------------------------------------------------------------
__global__ __launch_bounds__(256)
void proj_k(const float* __restrict__ uc, const float* __restrict__ Wx,
            float* __restrict__ proj) {
  __shared__ float As[64][32];
  __shared__ float Bs[64][96];
  const int tid = threadIdx.x;
  const int row0 = blockIdx.x * 32;
  const int ty = tid >> 4, tx = tid & 15;   // ty: 2 rows each, tx: 6 cols each
  float acc[2][6];
  #pragma unroll
  for (int i = 0; i < 2; ++i)
    #pragma unroll
    for (int j = 0; j < 6; ++j) acc[i][j] = 0.f;

  for (int k0 = 0; k0 < DE; k0 += 64) {
    __syncthreads();
    #pragma unroll
    for (int q = 0; q < 2; ++q) {           // A tile: 32x64 = 512 float4
      const int f = q*256 + tid;
      const int rr = f >> 4, cc = (f & 15) << 2;
      float4 v = *(const float4*)(uc + (size_t)(row0+rr)*DE + k0 + cc);
      As[cc+0][rr]=v.x; As[cc+1][rr]=v.y; As[cc+2][rr]=v.z; As[cc+3][rr]=v.w;
    }
    #pragma unroll
    for (int q = 0; q < 6; ++q) {           // B tile: 96x64 = 1536 float4
      const int f = q*256 + tid;
      const int rr = f >> 4, cc = (f & 15) << 2;
      float4 v = *(const float4*)(Wx + (size_t)rr*DE + k0 + cc);
      Bs[cc+0][rr]=v.x; Bs[cc+1][rr]=v.y; Bs[cc+2][rr]=v.z; Bs[cc+3][rr]=v.w;
    }
    __syncthreads();
    #pragma unroll 8
    for (int k = 0; k < 64; ++k) {
      const float a0 = As[k][ty*2], a1 = As[k][ty*2+1];
      float b[6];
      #pragma unroll
      for (int j = 0; j < 6; ++j) b[j] = Bs[k][tx*6+j];
      #pragma unroll
      for (int j = 0; j < 6; ++j) {
        acc[0][j] = fmaf(a0, b[j], acc[0][j]);
        acc[1][j] = fmaf(a1, b[j], acc[1][j]);
      }
    }
  }
  #pragma unroll
  for (int i = 0; i < 2; ++i)
    #pragma unroll
    for (int j = 0; j < 6; ++j)
      proj[(size_t)(row0 + ty*2 + i)*96 + tx*6 + j] = acc[i][j];
}

// ---------------------------------------------------------------------------
// delta[M,2048] = softplus(dt[M,64] @ W_dt[2048,64]^T + b_dt). Single K pass.
// ---------------------------------------------------------------------------
__global__ __launch_bounds__(256)
void delta_k(const float* __restrict__ proj, const float* __restrict__ Wdt,
             const float* __restrict__ bdt, float* __restrict__ dl) {
  __shared__ float As[64][64];
  __shared__ float Bs[64][64];
  const int tid = threadIdx.x;
  const int row0 = blockIdx.y * 64, col0 = blockIdx.x * 64;
  const int ty = tid >> 4, tx = tid & 15;
  #pragma unroll
  for (int q = 0; q < 4; ++q) {             // each tile: 64x64 = 1024 float4
    const int f = q*256 + tid;
    const int rr = f >> 4, cc = (f & 15) << 2;
    float4 v = *(const float4*)(proj + (size_t)(row0+rr)*96 + 32 + cc);
    As[cc+0][rr]=v.x; As[cc+1][rr]=v.y; As[cc+2][rr]=v.z; As[cc+3][rr]=v.w;
    float4 w = *(const float4*)(Wdt + (size_t)(col0+rr)*64 + cc);
    Bs[cc+0][rr]=w.x; Bs[cc+1][rr]=w.y; Bs[cc+2][rr]=w.z; Bs[cc+3][rr]=w.w;
  }
  __syncthreads();
  float acc[4][4];
  #pragma unroll
  for (int i = 0; i < 4; ++i)
    #pragma unroll
    for (int j = 0; j < 4; ++j) acc[i][j] = 0.f;
  #pragma unroll 8
  for (int k = 0; k < 64; ++k) {
    const float4 a = *(const float4*)&As[k][ty*4];
    const float4 w = *(const float4*)&Bs[k][tx*4];
    const float a_[4]={a.x,a.y,a.z,a.w}, b_[4]={w.x,w.y,w.z,w.w};
    #pragma unroll
    for (int i = 0; i < 4; ++i)
      #pragma unroll
      for (int j = 0; j < 4; ++j)
        acc[i][j] = fmaf(a_[i], b_[j], acc[i][j]);
  }
  #pragma unroll
  for (int i = 0; i < 4; ++i) {
    const int m = row0 + ty*4 + i;
    #pragma unroll
    for (int j = 0; j < 4; ++j) {
      const int d = col0 + tx*4 + j;
      float v = acc[i][j] + bdt[d];
      float sp = (v > 20.f) ? v : log1pf(expf(v));
      dl[(size_t)m*DE + d] = sp;
    }
  }
}

// ---------------------------------------------------------------------------
// Chunked scan, phase 1: per (b, d, chunk) local scan from h=0.
// Stores hfinal (layout [b][c][n][d]) and sum of delta over the chunk.
// One thread per (b,d,chunk); h[16] in registers; B staged in LDS.
// ---------------------------------------------------------------------------
__global__ __launch_bounds__(256)
void scan_part1(const float* __restrict__ dl, const float* __restrict__ uc,
                const float* __restrict__ proj, const float* __restrict__ Alog,
                float* __restrict__ hX, float* __restrict__ sumdv) {
  __shared__ float Bsh[CL][NS];
  const int tid = threadIdx.x;
  const int d = blockIdx.x * 256 + tid;
  const int c = blockIdx.y;
  const int b = blockIdx.z;
  const size_t mt0 = (size_t)b * L_ + c * CL;
  if (tid < CL * NS / 4) {                       // 128 threads stage B tile
    const int t = tid >> 2, n4 = (tid & 3) * 4;
    float4 v = *(const float4*)(proj + (mt0 + t) * 96 + n4);
    Bsh[t][n4] = v.x; Bsh[t][n4+1] = v.y; Bsh[t][n4+2] = v.z; Bsh[t][n4+3] = v.w;
  }
  float An2[NS];                                 // A * log2(e)
  #pragma unroll
  for (int q = 0; q < 4; ++q) {
    float4 a = *(const float4*)(Alog + d * NS + q * 4);
    An2[q*4+0] = -__expf(a.x) * 1.44269504f;
    An2[q*4+1] = -__expf(a.y) * 1.44269504f;
    An2[q*4+2] = -__expf(a.z) * 1.44269504f;
    An2[q*4+3] = -__expf(a.w) * 1.44269504f;
  }
  __syncthreads();
  float h[NS];
  #pragma unroll
  for (int n = 0; n < NS; ++n) h[n] = 0.f;
  float sd = 0.f;
  size_t off = mt0 * DE + d;
  float dv = dl[off], uv = uc[off];
  for (int t = 0; t < CL; ++t) {
    float dvn = 0.f, uvn = 0.f;
    if (t + 1 < CL) { dvn = dl[off + DE]; uvn = uc[off + DE]; }
    sd += dv;
    const float du = dv * uv;
    #pragma unroll
    for (int n = 0; n < NS; ++n) {
      const float dA = exp2f(dv * An2[n]);
      h[n] = fmaf(dA, h[n], du * Bsh[t][n]);
    }
    dv = dvn; uv = uvn; off += DE;
  }
  const size_t xb = (size_t)(b * NC + c) * NS * DE + d;
  #pragma unroll
  for (int n = 0; n < NS; ++n) hX[xb + (size_t)n * DE] = h[n];
  sumdv[(size_t)(b * NC + c) * DE + d] = sd;
}

// ---------------------------------------------------------------------------
// Chunked scan, phase 2: sequential combine over chunks (in place).
// One thread per (b,n,d). After this, hX[b][c][n][d] holds the TRUE h at
// the START of chunk c.
// ---------------------------------------------------------------------------
__global__ __launch_bounds__(256)
void scan_combine(float* __restrict__ hX, const float* __restrict__ sumdv,
                  const float* __restrict__ Alog) {
  const int tid = threadIdx.x;
  const int d = blockIdx.x * 256 + tid;
  const int n = blockIdx.y;
  const int b = blockIdx.z;
  const float An2 = -__expf(Alog[d * NS + n]) * 1.44269504f;
  float H = 0.f;
  for (int c = 0; c < NC; ++c) {
    const size_t xi = ((size_t)(b * NC + c) * NS + n) * DE + d;
    const float hf = hX[xi];
    const float sd = sumdv[(size_t)(b * NC + c) * DE + d];
    hX[xi] = H;                                  // true chunk-start state
    H = fmaf(exp2f(sd * An2), H, hf);            // advance past chunk c
  }
}

// ---------------------------------------------------------------------------
// Chunked scan, phase 3: re-run each chunk from its true start state,
// produce y_t and the fused epilogue (y + u*D) * silu(z) into xz[:, :2048].
// ---------------------------------------------------------------------------
__global__ __launch_bounds__(256)
void scan_part2(const float* __restrict__ dl, const float* __restrict__ uc,
                const float* __restrict__ proj, const float* __restrict__ hX,
                const float* __restrict__ Alog, const float* __restrict__ Dv,
                float* __restrict__ xz) {
  __shared__ float Bsh[CL][NS];
  __shared__ float Csh[CL][NS];
  const int tid = threadIdx.x;
  const int d = blockIdx.x * 256 + tid;
  const int c = blockIdx.y;
  const int b = blockIdx.z;
  const size_t mt0 = (size_t)b * L_ + c * CL;
  if (tid < 128) {                               // stage B tile
    const int t = tid >> 2, n4 = (tid & 3) * 4;
    float4 v = *(const float4*)(proj + (mt0 + t) * 96 + n4);
    Bsh[t][n4] = v.x; Bsh[t][n4+1] = v.y; Bsh[t][n4+2] = v.z; Bsh[t][n4+3] = v.w;
  } else {                                       // stage C tile
    const int u = tid - 128;
    const int t = u >> 2, n4 = (u & 3) * 4;
    float4 v = *(const float4*)(proj + (mt0 + t) * 96 + 16 + n4);
    Csh[t][n4] = v.x; Csh[t][n4+1] = v.y; Csh[t][n4+2] = v.z; Csh[t][n4+3] = v.w;
  }
  float An2[NS];
  #pragma unroll
  for (int q = 0; q < 4; ++q) {
    float4 a = *(const float4*)(Alog + d * NS + q * 4);
    An2[q*4+0] = -__expf(a.x) * 1.44269504f;
    An2[q*4+1] = -__expf(a.y) * 1.44269504f;
    An2[q*4+2] = -__expf(a.z) * 1.44269504f;
    An2[q*4+3] = -__expf(a.w) * 1.44269504f;
  }
  const float Dd = Dv[d];
  float h[NS];
  const size_t xb = (size_t)(b * NC + c) * NS * DE + d;
  #pragma unroll
  for (int n = 0; n < NS; ++n) h[n] = hX[xb + (size_t)n * DE];
  __syncthreads();
  size_t off = mt0 * DE + d;
  size_t zoff = mt0 * 4096 + d;
  float dv = dl[off], uv = uc[off];
  for (int t = 0; t < CL; ++t) {
    float dvn = 0.f, uvn = 0.f;
    if (t + 1 < CL) { dvn = dl[off + DE]; uvn = uc[off + DE]; }
    const float zv = xz[zoff + 2048];
    const float du = dv * uv;
    float y = 0.f;
    #pragma unroll
    for (int n = 0; n < NS; ++n) {
      const float dA = exp2f(dv * An2[n]);
      h[n] = fmaf(dA, h[n], du * Bsh[t][n]);
      y = fmaf(h[n], Csh[t][n], y);
    }
    y = fmaf(uv, Dd, y);
    const float sz = zv / (1.f + __expf(-zv));
    xz[zoff] = y * sz;                           // overwrite dead u-half
    dv = dvn; uv = uvn; off += DE; zoff += 4096;
  }
}

// ---------------------------------------------------------------------------
extern "C" void kernel_launch(void* const* d_in, const int* in_sizes, int n_in,
                              void* d_out, int out_size, void* d_ws, size_t ws_size,
                              hipStream_t stream) {
  const float* x    = (const float*)d_in[0];
  const float* Win  = (const float*)d_in[1];
  const float* cw   = (const float*)d_in[2];
  const float* cb   = (const float*)d_in[3];
  const float* Wx   = (const float*)d_in[4];
  const float* Wdt  = (const float*)d_in[5];
  const float* bdt  = (const float*)d_in[6];
  const float* Alog = (const float*)d_in[7];
  const float* Dv   = (const float*)d_in[8];
  const float* Wout = (const float*)d_in[9];
  float* out = (float*)d_out;
  float* ws  = (float*)d_ws;

  float* xz    = ws;                          // 16777216 f32 (u | z); y over u
  float* uc    = ws + 16777216;               //  8388608
  float* proj  = ws + 25165824;               //   393216
  float* dl    = ws + 25559040;               //  8388608
  float* hX    = ws + 33947648;               //  4194304  [b][c][n][d]
  float* sumdv = ws + 38141952;               //   262144  [b][c][d]

  // 1) xz = x @ W_in^T
  gemm_abt_128<<<dim3(32, 32), 256, 0, stream>>>(x, DM, Win, DM, xz, 4096, DM);
  // 2) uc = silu(depthwise_conv3(u) + conv_b)
  conv_silu_k<<<8192, 256, 0, stream>>>(xz, cw, cb, uc);
  // 3) proj = uc @ W_xproj^T
  proj_k<<<128, 256, 0, stream>>>(uc, Wx, proj);
  // 4) delta = softplus(dt @ W_dt^T + b_dt)
  delta_k<<<dim3(32, 64), 256, 0, stream>>>(proj, Wdt, bdt, dl);
  // 5) chunked selective scan -> y (into xz[:, :2048])
  scan_part1<<<dim3(DE/256, NC, B_), 256, 0, stream>>>(dl, uc, proj, Alog, hX, sumdv);
  scan_combine<<<dim3(DE/256, NS, B_), 256, 0, stream>>>(hX, sumdv, Alog);
  scan_part2<<<dim3(DE/256, NC, B_), 256, 0, stream>>>(dl, uc, proj, hX, Alog, Dv, xz);
  // 6) out = y @ W_out^T
  gemm_abt_128<<<dim3(8, 32), 256, 0, stream>>>(xz, 4096, Wout, DE, out, DM, DE);
}

// Round 3
// 440.951 us; speedup vs baseline: 3.8705x; 2.1889x over previous
//
#include <hip/hip_runtime.h>
#include <math.h>

#define B_   4
#define L_   1024
#define DM   1024
#define DE   2048
#define NS   16
#define M_   (B_*L_)   // 4096
#define NC   32        // scan chunks
#define CL   32        // chunk length (NC*CL == L_)

typedef __attribute__((ext_vector_type(8))) short bf16x8;
typedef __attribute__((ext_vector_type(4))) float f32x4;

#define AS1 __attribute__((address_space(1)))
#define AS3 __attribute__((address_space(3)))

__device__ __forceinline__ void gload_lds16(const void* g, void* l) {
  __builtin_amdgcn_global_load_lds((const AS1 unsigned int*)g,
                                   (AS3 unsigned int*)l, 16, 0, 0);
}

__device__ __forceinline__ unsigned short f2bf(float f) {
  unsigned int u = __builtin_bit_cast(unsigned int, f);
  u = (u + 0x7fffu + ((u >> 16) & 1u)) >> 16;   // round-to-nearest-even
  return (unsigned short)u;
}

// ---------------------------------------------------------------------------
// f32 -> bf16 conversion, 8 elements/thread. n must be multiple of 2048.
// ---------------------------------------------------------------------------
__global__ __launch_bounds__(256)
void f2bf_k(const float* __restrict__ src, unsigned short* __restrict__ dst) {
  const size_t i = ((size_t)blockIdx.x * 256 + threadIdx.x) * 8;
  float4 a = *(const float4*)(src + i);
  float4 b = *(const float4*)(src + i + 4);
  unsigned short o[8] = {f2bf(a.x), f2bf(a.y), f2bf(a.z), f2bf(a.w),
                         f2bf(b.x), f2bf(b.y), f2bf(b.z), f2bf(b.w)};
  *(ulonglong2*)(dst + i) = *(const ulonglong2*)o;
}

// ---------------------------------------------------------------------------
// bf16 MFMA GEMM (m97 structure): C[M,N]f32 = A[M,K]bf16 @ Bt[N,K]bf16^T.
// 128x128 tile, BK=32, 256 threads (4 waves, 2x2 of 64x64), global_load_lds.
// M,N multiples of 128; K multiple of 32.
// ---------------------------------------------------------------------------
__global__ __launch_bounds__(256)
void gemm_bf16_abt(const unsigned short* __restrict__ A, int lda,
                   const unsigned short* __restrict__ Bt, int ldb,
                   float* __restrict__ C, int ldc, int K) {
  __shared__ unsigned short Asl[128 * 32];
  __shared__ unsigned short Bsl[128 * 32];
  const int tid  = threadIdx.x;
  const int lane = tid & 63;
  const int wave = tid >> 6;
  const int row0 = blockIdx.y * 128, col0 = blockIdx.x * 128;
  const int wr = (wave >> 1) * 64, wc = (wave & 1) * 64;

  // staging: chunk c in [0,512), 16B each; row = c>>2, col = (c&3)*8
  const int c0 = tid, c1 = 256 + tid;
  const unsigned short* Ag0 = A + (size_t)(row0 + (c0 >> 2)) * lda + ((c0 & 3) << 3);
  const unsigned short* Ag1 = A + (size_t)(row0 + (c1 >> 2)) * lda + ((c1 & 3) << 3);
  const unsigned short* Bg0 = Bt + (size_t)(col0 + (c0 >> 2)) * ldb + ((c0 & 3) << 3);
  const unsigned short* Bg1 = Bt + (size_t)(col0 + (c1 >> 2)) * ldb + ((c1 & 3) << 3);
  unsigned short* Al0 = Asl + ((wave << 6) << 3);            // wave-uniform bases
  unsigned short* Al1 = Asl + ((256 + (wave << 6)) << 3);
  unsigned short* Bl0 = Bsl + ((wave << 6) << 3);
  unsigned short* Bl1 = Bsl + ((256 + (wave << 6)) << 3);

  const int frow = lane & 15;
  const int fk   = (lane >> 4) << 3;
  const unsigned short* Afr = Asl + ((wr + frow) << 5) + fk;
  const unsigned short* Bfr = Bsl + ((wc + frow) << 5) + fk;

  f32x4 acc[4][4];
  #pragma unroll
  for (int m = 0; m < 4; ++m)
    #pragma unroll
    for (int n = 0; n < 4; ++n) acc[m][n] = (f32x4){0.f, 0.f, 0.f, 0.f};

  for (int k0 = 0; k0 < K; k0 += 32) {
    __syncthreads();
    gload_lds16(Ag0 + k0, Al0);
    gload_lds16(Ag1 + k0, Al1);
    gload_lds16(Bg0 + k0, Bl0);
    gload_lds16(Bg1 + k0, Bl1);
    __syncthreads();                    // compiler drains vmcnt before barrier
    bf16x8 af[4], bfr[4];
    #pragma unroll
    for (int m = 0; m < 4; ++m) af[m]  = *(const bf16x8*)(Afr + (m << 9));
    #pragma unroll
    for (int n = 0; n < 4; ++n) bfr[n] = *(const bf16x8*)(Bfr + (n << 9));
    #pragma unroll
    for (int m = 0; m < 4; ++m)
      #pragma unroll
      for (int n = 0; n < 4; ++n)
        acc[m][n] = __builtin_amdgcn_mfma_f32_16x16x32_bf16(af[m], bfr[n], acc[m][n], 0, 0, 0);
  }

  const int r4 = (lane >> 4) << 2;
  #pragma unroll
  for (int m = 0; m < 4; ++m)
    #pragma unroll
    for (int n = 0; n < 4; ++n) {
      float* Cp = C + (size_t)(row0 + wr + m * 16 + r4) * ldc + col0 + wc + n * 16 + (lane & 15);
      #pragma unroll
      for (int r = 0; r < 4; ++r) Cp[(size_t)r * ldc] = acc[m][n][r];
    }
}

// ---------------------------------------------------------------------------
// Depthwise conv(k=3, pad 1) + bias + SiLU.  u = xz[:, :2048] (row stride 4096)
// ---------------------------------------------------------------------------
__global__ __launch_bounds__(256)
void conv_silu_k(const float* __restrict__ xz, const float* __restrict__ cw,
                 const float* __restrict__ cb, float* __restrict__ uc) {
  const int g = blockIdx.x * 256 + threadIdx.x;   // [0, M_*DE/4)
  const int m = g >> 9;                            // DE/4 = 512 float4 per row
  const int d4 = (g & 511) << 2;
  const int l = m & (L_ - 1);
  const float* row = xz + (size_t)m * 4096 + d4;
  float4 cur = *(const float4*)row;
  float4 prv = make_float4(0.f,0.f,0.f,0.f);
  float4 nxt = make_float4(0.f,0.f,0.f,0.f);
  if (l > 0)      prv = *(const float4*)(row - 4096);
  if (l < L_ - 1) nxt = *(const float4*)(row + 4096);
  const float pc[4] = {prv.x,prv.y,prv.z,prv.w};
  const float cc[4] = {cur.x,cur.y,cur.z,cur.w};
  const float nc[4] = {nxt.x,nxt.y,nxt.z,nxt.w};
  float o[4];
  #pragma unroll
  for (int i = 0; i < 4; ++i) {
    const int d = d4 + i;
    float v = cb[d] + cw[d*3]*pc[i] + cw[d*3+1]*cc[i] + cw[d*3+2]*nc[i];
    o[i] = v / (1.f + __expf(-v));                // SiLU
  }
  *(float4*)(uc + (size_t)m * DE + d4) = make_float4(o[0],o[1],o[2],o[3]);
}

// ---------------------------------------------------------------------------
// proj[M,96] = uc[M,2048] @ W_xproj[96,2048]^T.  BM=32, BN=96, BK=64.
// ---------------------------------------------------------------------------
__global__ __launch_bounds__(256)
void proj_k(const float* __restrict__ uc, const float* __restrict__ Wx,
            float* __restrict__ proj) {
  __shared__ float As[64][32];
  __shared__ float Bs[64][96];
  const int tid = threadIdx.x;
  const int row0 = blockIdx.x * 32;
  const int ty = tid >> 4, tx = tid & 15;
  float acc[2][6];
  #pragma unroll
  for (int i = 0; i < 2; ++i)
    #pragma unroll
    for (int j = 0; j < 6; ++j) acc[i][j] = 0.f;

  for (int k0 = 0; k0 < DE; k0 += 64) {
    __syncthreads();
    #pragma unroll
    for (int q = 0; q < 2; ++q) {
      const int f = q*256 + tid;
      const int rr = f >> 4, cc = (f & 15) << 2;
      float4 v = *(const float4*)(uc + (size_t)(row0+rr)*DE + k0 + cc);
      As[cc+0][rr]=v.x; As[cc+1][rr]=v.y; As[cc+2][rr]=v.z; As[cc+3][rr]=v.w;
    }
    #pragma unroll
    for (int q = 0; q < 6; ++q) {
      const int f = q*256 + tid;
      const int rr = f >> 4, cc = (f & 15) << 2;
      float4 v = *(const float4*)(Wx + (size_t)rr*DE + k0 + cc);
      Bs[cc+0][rr]=v.x; Bs[cc+1][rr]=v.y; Bs[cc+2][rr]=v.z; Bs[cc+3][rr]=v.w;
    }
    __syncthreads();
    #pragma unroll 8
    for (int k = 0; k < 64; ++k) {
      const float a0 = As[k][ty*2], a1 = As[k][ty*2+1];
      float b[6];
      #pragma unroll
      for (int j = 0; j < 6; ++j) b[j] = Bs[k][tx*6+j];
      #pragma unroll
      for (int j = 0; j < 6; ++j) {
        acc[0][j] = fmaf(a0, b[j], acc[0][j]);
        acc[1][j] = fmaf(a1, b[j], acc[1][j]);
      }
    }
  }
  #pragma unroll
  for (int i = 0; i < 2; ++i)
    #pragma unroll
    for (int j = 0; j < 6; ++j)
      proj[(size_t)(row0 + ty*2 + i)*96 + tx*6 + j] = acc[i][j];
}

// ---------------------------------------------------------------------------
// delta[M,2048] = softplus(dt[M,64] @ W_dt[2048,64]^T + b_dt). Single K pass.
// ---------------------------------------------------------------------------
__global__ __launch_bounds__(256)
void delta_k(const float* __restrict__ proj, const float* __restrict__ Wdt,
             const float* __restrict__ bdt, float* __restrict__ dl) {
  __shared__ float As[64][64];
  __shared__ float Bs[64][64];
  const int tid = threadIdx.x;
  const int row0 = blockIdx.y * 64, col0 = blockIdx.x * 64;
  const int ty = tid >> 4, tx = tid & 15;
  #pragma unroll
  for (int q = 0; q < 4; ++q) {
    const int f = q*256 + tid;
    const int rr = f >> 4, cc = (f & 15) << 2;
    float4 v = *(const float4*)(proj + (size_t)(row0+rr)*96 + 32 + cc);
    As[cc+0][rr]=v.x; As[cc+1][rr]=v.y; As[cc+2][rr]=v.z; As[cc+3][rr]=v.w;
    float4 w = *(const float4*)(Wdt + (size_t)(col0+rr)*64 + cc);
    Bs[cc+0][rr]=w.x; Bs[cc+1][rr]=w.y; Bs[cc+2][rr]=w.z; Bs[cc+3][rr]=w.w;
  }
  __syncthreads();
  float acc[4][4];
  #pragma unroll
  for (int i = 0; i < 4; ++i)
    #pragma unroll
    for (int j = 0; j < 4; ++j) acc[i][j] = 0.f;
  #pragma unroll 8
  for (int k = 0; k < 64; ++k) {
    const float4 a = *(const float4*)&As[k][ty*4];
    const float4 w = *(const float4*)&Bs[k][tx*4];
    const float a_[4]={a.x,a.y,a.z,a.w}, b_[4]={w.x,w.y,w.z,w.w};
    #pragma unroll
    for (int i = 0; i < 4; ++i)
      #pragma unroll
      for (int j = 0; j < 4; ++j)
        acc[i][j] = fmaf(a_[i], b_[j], acc[i][j]);
  }
  #pragma unroll
  for (int i = 0; i < 4; ++i) {
    const int m = row0 + ty*4 + i;
    #pragma unroll
    for (int j = 0; j < 4; ++j) {
      const int d = col0 + tx*4 + j;
      float v = acc[i][j] + bdt[d];
      float sp = (v > 20.f) ? v : log1pf(expf(v));
      dl[(size_t)m*DE + d] = sp;
    }
  }
}

// ---------------------------------------------------------------------------
// Chunked scan, phase 1: per (b, d, chunk) local scan from h=0.
// ---------------------------------------------------------------------------
__global__ __launch_bounds__(256)
void scan_part1(const float* __restrict__ dl, const float* __restrict__ uc,
                const float* __restrict__ proj, const float* __restrict__ Alog,
                float* __restrict__ hX, float* __restrict__ sumdv) {
  __shared__ float Bsh[CL][NS];
  const int tid = threadIdx.x;
  const int d = blockIdx.x * 256 + tid;
  const int c = blockIdx.y;
  const int b = blockIdx.z;
  const size_t mt0 = (size_t)b * L_ + c * CL;
  if (tid < CL * NS / 4) {
    const int t = tid >> 2, n4 = (tid & 3) * 4;
    float4 v = *(const float4*)(proj + (mt0 + t) * 96 + n4);
    Bsh[t][n4] = v.x; Bsh[t][n4+1] = v.y; Bsh[t][n4+2] = v.z; Bsh[t][n4+3] = v.w;
  }
  float An2[NS];
  #pragma unroll
  for (int q = 0; q < 4; ++q) {
    float4 a = *(const float4*)(Alog + d * NS + q * 4);
    An2[q*4+0] = -__expf(a.x) * 1.44269504f;
    An2[q*4+1] = -__expf(a.y) * 1.44269504f;
    An2[q*4+2] = -__expf(a.z) * 1.44269504f;
    An2[q*4+3] = -__expf(a.w) * 1.44269504f;
  }
  __syncthreads();
  float h[NS];
  #pragma unroll
  for (int n = 0; n < NS; ++n) h[n] = 0.f;
  float sd = 0.f;
  size_t off = mt0 * DE + d;
  float dv = dl[off], uv = uc[off];
  for (int t = 0; t < CL; ++t) {
    float dvn = 0.f, uvn = 0.f;
    if (t + 1 < CL) { dvn = dl[off + DE]; uvn = uc[off + DE]; }
    sd += dv;
    const float du = dv * uv;
    #pragma unroll
    for (int n = 0; n < NS; ++n) {
      const float dA = exp2f(dv * An2[n]);
      h[n] = fmaf(dA, h[n], du * Bsh[t][n]);
    }
    dv = dvn; uv = uvn; off += DE;
  }
  const size_t xb = (size_t)(b * NC + c) * NS * DE + d;
  #pragma unroll
  for (int n = 0; n < NS; ++n) hX[xb + (size_t)n * DE] = h[n];
  sumdv[(size_t)(b * NC + c) * DE + d] = sd;
}

// ---------------------------------------------------------------------------
// Chunked scan, phase 2: sequential combine over chunks (in place).
// ---------------------------------------------------------------------------
__global__ __launch_bounds__(256)
void scan_combine(float* __restrict__ hX, const float* __restrict__ sumdv,
                  const float* __restrict__ Alog) {
  const int tid = threadIdx.x;
  const int d = blockIdx.x * 256 + tid;
  const int n = blockIdx.y;
  const int b = blockIdx.z;
  const float An2 = -__expf(Alog[d * NS + n]) * 1.44269504f;
  float H = 0.f;
  for (int c = 0; c < NC; ++c) {
    const size_t xi = ((size_t)(b * NC + c) * NS + n) * DE + d;
    const float hf = hX[xi];
    const float sd = sumdv[(size_t)(b * NC + c) * DE + d];
    hX[xi] = H;
    H = fmaf(exp2f(sd * An2), H, hf);
  }
}

// ---------------------------------------------------------------------------
// Chunked scan, phase 3: re-run chunk from true start, fused epilogue
// (y + u*D) * silu(z) written as bf16 into ybf[M, DE].
// ---------------------------------------------------------------------------
__global__ __launch_bounds__(256)
void scan_part2(const float* __restrict__ dl, const float* __restrict__ uc,
                const float* __restrict__ proj, const float* __restrict__ hX,
                const float* __restrict__ Alog, const float* __restrict__ Dv,
                const float* __restrict__ xz, unsigned short* __restrict__ ybf) {
  __shared__ float Bsh[CL][NS];
  __shared__ float Csh[CL][NS];
  const int tid = threadIdx.x;
  const int d = blockIdx.x * 256 + tid;
  const int c = blockIdx.y;
  const int b = blockIdx.z;
  const size_t mt0 = (size_t)b * L_ + c * CL;
  if (tid < 128) {
    const int t = tid >> 2, n4 = (tid & 3) * 4;
    float4 v = *(const float4*)(proj + (mt0 + t) * 96 + n4);
    Bsh[t][n4] = v.x; Bsh[t][n4+1] = v.y; Bsh[t][n4+2] = v.z; Bsh[t][n4+3] = v.w;
  } else {
    const int u = tid - 128;
    const int t = u >> 2, n4 = (u & 3) * 4;
    float4 v = *(const float4*)(proj + (mt0 + t) * 96 + 16 + n4);
    Csh[t][n4] = v.x; Csh[t][n4+1] = v.y; Csh[t][n4+2] = v.z; Csh[t][n4+3] = v.w;
  }
  float An2[NS];
  #pragma unroll
  for (int q = 0; q < 4; ++q) {
    float4 a = *(const float4*)(Alog + d * NS + q * 4);
    An2[q*4+0] = -__expf(a.x) * 1.44269504f;
    An2[q*4+1] = -__expf(a.y) * 1.44269504f;
    An2[q*4+2] = -__expf(a.z) * 1.44269504f;
    An2[q*4+3] = -__expf(a.w) * 1.44269504f;
  }
  const float Dd = Dv[d];
  float h[NS];
  const size_t xb = (size_t)(b * NC + c) * NS * DE + d;
  #pragma unroll
  for (int n = 0; n < NS; ++n) h[n] = hX[xb + (size_t)n * DE];
  __syncthreads();
  size_t off = mt0 * DE + d;
  size_t zoff = mt0 * 4096 + d;
  float dv = dl[off], uv = uc[off];
  for (int t = 0; t < CL; ++t) {
    float dvn = 0.f, uvn = 0.f;
    if (t + 1 < CL) { dvn = dl[off + DE]; uvn = uc[off + DE]; }
    const float zv = xz[zoff + 2048];
    const float du = dv * uv;
    float y = 0.f;
    #pragma unroll
    for (int n = 0; n < NS; ++n) {
      const float dA = exp2f(dv * An2[n]);
      h[n] = fmaf(dA, h[n], du * Bsh[t][n]);
      y = fmaf(h[n], Csh[t][n], y);
    }
    y = fmaf(uv, Dd, y);
    const float sz = zv / (1.f + __expf(-zv));
    ybf[off] = f2bf(y * sz);
    dv = dvn; uv = uvn; off += DE; zoff += 4096;
  }
}

// ---------------------------------------------------------------------------
extern "C" void kernel_launch(void* const* d_in, const int* in_sizes, int n_in,
                              void* d_out, int out_size, void* d_ws, size_t ws_size,
                              hipStream_t stream) {
  const float* x    = (const float*)d_in[0];
  const float* Win  = (const float*)d_in[1];
  const float* cw   = (const float*)d_in[2];
  const float* cb   = (const float*)d_in[3];
  const float* Wx   = (const float*)d_in[4];
  const float* Wdt  = (const float*)d_in[5];
  const float* bdt  = (const float*)d_in[6];
  const float* Alog = (const float*)d_in[7];
  const float* Dv   = (const float*)d_in[8];
  const float* Wout = (const float*)d_in[9];
  float* out = (float*)d_out;
  float* ws  = (float*)d_ws;

  float*          xz    = ws;                    // 16777216 f32 (u | z)
  float*          uc    = ws + 16777216;         //  8388608
  float*          proj  = ws + 25165824;         //   393216
  float*          dl    = ws + 25559040;         //  8388608
  float*          hX    = ws + 33947648;         //  4194304  [b][c][n][d]
  float*          sumdv = ws + 38141952;         //   262144
  unsigned short* x_bf   = (unsigned short*)(ws + 38404096);  // 4194304 bf16
  unsigned short* Win_bf  = (unsigned short*)(ws + 40501248); // 4194304 bf16
  unsigned short* Wout_bf = (unsigned short*)(ws + 42598400); // 2097152 bf16
  unsigned short* y_bf    = (unsigned short*)(ws + 43646976); // 8388608 bf16

  // 0) weight/input conversion to bf16
  f2bf_k<<<2048, 256, 0, stream>>>(x,   x_bf);
  f2bf_k<<<2048, 256, 0, stream>>>(Win, Win_bf);
  f2bf_k<<<1024, 256, 0, stream>>>(Wout, Wout_bf);
  // 1) xz = x @ W_in^T  (bf16 MFMA)
  gemm_bf16_abt<<<dim3(32, 32), 256, 0, stream>>>(x_bf, DM, Win_bf, DM, xz, 4096, DM);
  // 2) uc = silu(depthwise_conv3(u) + conv_b)
  conv_silu_k<<<8192, 256, 0, stream>>>(xz, cw, cb, uc);
  // 3) proj = uc @ W_xproj^T
  proj_k<<<128, 256, 0, stream>>>(uc, Wx, proj);
  // 4) delta = softplus(dt @ W_dt^T + b_dt)
  delta_k<<<dim3(32, 64), 256, 0, stream>>>(proj, Wdt, bdt, dl);
  // 5) chunked selective scan -> y_bf
  scan_part1<<<dim3(DE/256, NC, B_), 256, 0, stream>>>(dl, uc, proj, Alog, hX, sumdv);
  scan_combine<<<dim3(DE/256, NS, B_), 256, 0, stream>>>(hX, sumdv, Alog);
  scan_part2<<<dim3(DE/256, NC, B_), 256, 0, stream>>>(dl, uc, proj, hX, Alog, Dv, xz, y_bf);
  // 6) out = y @ W_out^T  (bf16 MFMA)
  gemm_bf16_abt<<<dim3(8, 32), 256, 0, stream>>>(y_bf, DE, Wout_bf, DE, out, DM, DE);
}

// Round 4
// 292.899 us; speedup vs baseline: 5.8269x; 1.5055x over previous
//
#include <hip/hip_runtime.h>
#include <math.h>

#define B_   4
#define L_   1024
#define DM   1024
#define DE   2048
#define NS   16
#define M_   (B_*L_)   // 4096
#define NC   32        // scan chunks
#define CL   32        // chunk length (NC*CL == L_)

typedef __attribute__((ext_vector_type(8))) short bf16x8;
typedef __attribute__((ext_vector_type(4))) float f32x4;

#define AS1 __attribute__((address_space(1)))
#define AS3 __attribute__((address_space(3)))

__device__ __forceinline__ void gload_lds16(const void* g, void* l) {
  __builtin_amdgcn_global_load_lds((const AS1 unsigned int*)g,
                                   (AS3 unsigned int*)l, 16, 0, 0);
}

__device__ __forceinline__ unsigned short f2bf(float f) {
  unsigned int u = __builtin_bit_cast(unsigned int, f);
  u = (u + 0x7fffu + ((u >> 16) & 1u)) >> 16;   // round-to-nearest-even
  return (unsigned short)u;
}

// ---------------------------------------------------------------------------
// f32 -> bf16 conversion, 8 elements/thread. n must be multiple of 2048.
// ---------------------------------------------------------------------------
__global__ __launch_bounds__(256)
void f2bf_k(const float* __restrict__ src, unsigned short* __restrict__ dst) {
  const size_t i = ((size_t)blockIdx.x * 256 + threadIdx.x) * 8;
  float4 a = *(const float4*)(src + i);
  float4 b = *(const float4*)(src + i + 4);
  unsigned short o[8] = {f2bf(a.x), f2bf(a.y), f2bf(a.z), f2bf(a.w),
                         f2bf(b.x), f2bf(b.y), f2bf(b.z), f2bf(b.w)};
  *(ulonglong2*)(dst + i) = *(const ulonglong2*)o;
}

// ---------------------------------------------------------------------------
// W_xproj[96][2048] f32 -> padded [128][2048] bf16 (rows 96..127 = 0)
// ---------------------------------------------------------------------------
__global__ __launch_bounds__(256)
void wxpad_k(const float* __restrict__ Wx, unsigned short* __restrict__ Wxp) {
  const size_t i = ((size_t)blockIdx.x * 256 + threadIdx.x) * 8;
  const int row = (int)(i >> 11);
  unsigned short o[8] = {0,0,0,0,0,0,0,0};
  if (row < 96) {
    float4 a = *(const float4*)(Wx + i);
    float4 b = *(const float4*)(Wx + i + 4);
    o[0]=f2bf(a.x); o[1]=f2bf(a.y); o[2]=f2bf(a.z); o[3]=f2bf(a.w);
    o[4]=f2bf(b.x); o[5]=f2bf(b.y); o[6]=f2bf(b.z); o[7]=f2bf(b.w);
  }
  *(ulonglong2*)(Wxp + i) = *(const ulonglong2*)o;
}

// ---------------------------------------------------------------------------
// bf16 MFMA GEMM (m97 structure): C[M,N]f32 = A[M,K]bf16 @ Bt[N,K]bf16^T.
// 128x128 tile, BK=32, 256 threads (4 waves, 2x2 of 64x64), global_load_lds.
// ---------------------------------------------------------------------------
__global__ __launch_bounds__(256)
void gemm_bf16_abt(const unsigned short* __restrict__ A, int lda,
                   const unsigned short* __restrict__ Bt, int ldb,
                   float* __restrict__ C, int ldc, int K) {
  __shared__ unsigned short Asl[128 * 32];
  __shared__ unsigned short Bsl[128 * 32];
  const int tid  = threadIdx.x;
  const int lane = tid & 63;
  const int wave = tid >> 6;
  const int row0 = blockIdx.y * 128, col0 = blockIdx.x * 128;
  const int wr = (wave >> 1) * 64, wc = (wave & 1) * 64;

  const int c0 = tid, c1 = 256 + tid;
  const unsigned short* Ag0 = A + (size_t)(row0 + (c0 >> 2)) * lda + ((c0 & 3) << 3);
  const unsigned short* Ag1 = A + (size_t)(row0 + (c1 >> 2)) * lda + ((c1 & 3) << 3);
  const unsigned short* Bg0 = Bt + (size_t)(col0 + (c0 >> 2)) * ldb + ((c0 & 3) << 3);
  const unsigned short* Bg1 = Bt + (size_t)(col0 + (c1 >> 2)) * ldb + ((c1 & 3) << 3);
  unsigned short* Al0 = Asl + ((wave << 6) << 3);
  unsigned short* Al1 = Asl + ((256 + (wave << 6)) << 3);
  unsigned short* Bl0 = Bsl + ((wave << 6) << 3);
  unsigned short* Bl1 = Bsl + ((256 + (wave << 6)) << 3);

  const int frow = lane & 15;
  const int fk   = (lane >> 4) << 3;
  const unsigned short* Afr = Asl + ((wr + frow) << 5) + fk;
  const unsigned short* Bfr = Bsl + ((wc + frow) << 5) + fk;

  f32x4 acc[4][4];
  #pragma unroll
  for (int m = 0; m < 4; ++m)
    #pragma unroll
    for (int n = 0; n < 4; ++n) acc[m][n] = (f32x4){0.f, 0.f, 0.f, 0.f};

  for (int k0 = 0; k0 < K; k0 += 32) {
    __syncthreads();
    gload_lds16(Ag0 + k0, Al0);
    gload_lds16(Ag1 + k0, Al1);
    gload_lds16(Bg0 + k0, Bl0);
    gload_lds16(Bg1 + k0, Bl1);
    __syncthreads();
    bf16x8 af[4], bfr[4];
    #pragma unroll
    for (int m = 0; m < 4; ++m) af[m]  = *(const bf16x8*)(Afr + (m << 9));
    #pragma unroll
    for (int n = 0; n < 4; ++n) bfr[n] = *(const bf16x8*)(Bfr + (n << 9));
    #pragma unroll
    for (int m = 0; m < 4; ++m)
      #pragma unroll
      for (int n = 0; n < 4; ++n)
        acc[m][n] = __builtin_amdgcn_mfma_f32_16x16x32_bf16(af[m], bfr[n], acc[m][n], 0, 0, 0);
  }

  const int r4 = (lane >> 4) << 2;
  #pragma unroll
  for (int m = 0; m < 4; ++m)
    #pragma unroll
    for (int n = 0; n < 4; ++n) {
      float* Cp = C + (size_t)(row0 + wr + m * 16 + r4) * ldc + col0 + wc + n * 16 + (lane & 15);
      #pragma unroll
      for (int r = 0; r < 4; ++r) Cp[(size_t)r * ldc] = acc[m][n][r];
    }
}

// ---------------------------------------------------------------------------
// proj split-K MFMA: grid (ks=8, mtile=32). Each block: 128x128 tile over
// K range [ks*256, ks*256+256); writes f32 partial[ks][4096][128].
// ---------------------------------------------------------------------------
__global__ __launch_bounds__(256)
void proj_gemm_k(const unsigned short* __restrict__ A,      // uc_bf [4096][2048]
                 const unsigned short* __restrict__ Bt,     // Wxp   [128][2048]
                 float* __restrict__ part) {
  __shared__ unsigned short Asl[128 * 32];
  __shared__ unsigned short Bsl[128 * 32];
  const int tid  = threadIdx.x;
  const int lane = tid & 63;
  const int wave = tid >> 6;
  const int ks   = blockIdx.x;
  const int row0 = blockIdx.y * 128;
  const int wr = (wave >> 1) * 64, wc = (wave & 1) * 64;
  const int kbase = ks * 256;

  const int c0 = tid, c1 = 256 + tid;
  const unsigned short* Ag0 = A + (size_t)(row0 + (c0 >> 2)) * DE + ((c0 & 3) << 3) + kbase;
  const unsigned short* Ag1 = A + (size_t)(row0 + (c1 >> 2)) * DE + ((c1 & 3) << 3) + kbase;
  const unsigned short* Bg0 = Bt + (size_t)(c0 >> 2) * DE + ((c0 & 3) << 3) + kbase;
  const unsigned short* Bg1 = Bt + (size_t)(c1 >> 2) * DE + ((c1 & 3) << 3) + kbase;
  unsigned short* Al0 = Asl + ((wave << 6) << 3);
  unsigned short* Al1 = Asl + ((256 + (wave << 6)) << 3);
  unsigned short* Bl0 = Bsl + ((wave << 6) << 3);
  unsigned short* Bl1 = Bsl + ((256 + (wave << 6)) << 3);

  const int frow = lane & 15;
  const int fk   = (lane >> 4) << 3;
  const unsigned short* Afr = Asl + ((wr + frow) << 5) + fk;
  const unsigned short* Bfr = Bsl + ((wc + frow) << 5) + fk;

  f32x4 acc[4][4];
  #pragma unroll
  for (int m = 0; m < 4; ++m)
    #pragma unroll
    for (int n = 0; n < 4; ++n) acc[m][n] = (f32x4){0.f, 0.f, 0.f, 0.f};

  for (int k0 = 0; k0 < 256; k0 += 32) {
    __syncthreads();
    gload_lds16(Ag0 + k0, Al0);
    gload_lds16(Ag1 + k0, Al1);
    gload_lds16(Bg0 + k0, Bl0);
    gload_lds16(Bg1 + k0, Bl1);
    __syncthreads();
    bf16x8 af[4], bfr[4];
    #pragma unroll
    for (int m = 0; m < 4; ++m) af[m]  = *(const bf16x8*)(Afr + (m << 9));
    #pragma unroll
    for (int n = 0; n < 4; ++n) bfr[n] = *(const bf16x8*)(Bfr + (n << 9));
    #pragma unroll
    for (int m = 0; m < 4; ++m)
      #pragma unroll
      for (int n = 0; n < 4; ++n)
        acc[m][n] = __builtin_amdgcn_mfma_f32_16x16x32_bf16(af[m], bfr[n], acc[m][n], 0, 0, 0);
  }

  float* Cb = part + (size_t)ks * (M_ * 128) + (size_t)row0 * 128;
  const int r4 = (lane >> 4) << 2;
  #pragma unroll
  for (int m = 0; m < 4; ++m)
    #pragma unroll
    for (int n = 0; n < 4; ++n) {
      float* Cp = Cb + (size_t)(wr + m * 16 + r4) * 128 + wc + n * 16 + (lane & 15);
      #pragma unroll
      for (int r = 0; r < 4; ++r) Cp[(size_t)r * 128] = acc[m][n][r];
    }
}

// ---------------------------------------------------------------------------
// proj reduce: proj[m][j] = sum_ks part[ks][m][j], j in [0,96)
// ---------------------------------------------------------------------------
__global__ __launch_bounds__(256)
void proj_reduce_k(const float* __restrict__ part, float* __restrict__ proj) {
  const int g = blockIdx.x * 256 + threadIdx.x;   // [0, 4096*24)
  const int m = g / 24;
  const int j4 = (g - m * 24) * 4;
  float4 s = make_float4(0.f, 0.f, 0.f, 0.f);
  #pragma unroll
  for (int ks = 0; ks < 8; ++ks) {
    float4 v = *(const float4*)(part + (size_t)ks * (M_ * 128) + (size_t)m * 128 + j4);
    s.x += v.x; s.y += v.y; s.z += v.z; s.w += v.w;
  }
  *(float4*)(proj + (size_t)m * 96 + j4) = s;
}

// ---------------------------------------------------------------------------
// Depthwise conv(k=3, pad 1) + bias + SiLU. Writes f32 uc AND bf16 uc_bf.
// ---------------------------------------------------------------------------
__global__ __launch_bounds__(256)
void conv_silu_k(const float* __restrict__ xz, const float* __restrict__ cw,
                 const float* __restrict__ cb, float* __restrict__ uc,
                 unsigned short* __restrict__ uc_bf) {
  const int g = blockIdx.x * 256 + threadIdx.x;   // [0, M_*DE/4)
  const int m = g >> 9;
  const int d4 = (g & 511) << 2;
  const int l = m & (L_ - 1);
  const float* row = xz + (size_t)m * 4096 + d4;
  float4 cur = *(const float4*)row;
  float4 prv = make_float4(0.f,0.f,0.f,0.f);
  float4 nxt = make_float4(0.f,0.f,0.f,0.f);
  if (l > 0)      prv = *(const float4*)(row - 4096);
  if (l < L_ - 1) nxt = *(const float4*)(row + 4096);
  const float pc[4] = {prv.x,prv.y,prv.z,prv.w};
  const float cc[4] = {cur.x,cur.y,cur.z,cur.w};
  const float nc[4] = {nxt.x,nxt.y,nxt.z,nxt.w};
  float o[4];
  unsigned short ob[4];
  #pragma unroll
  for (int i = 0; i < 4; ++i) {
    const int d = d4 + i;
    float v = cb[d] + cw[d*3]*pc[i] + cw[d*3+1]*cc[i] + cw[d*3+2]*nc[i];
    o[i] = v / (1.f + __expf(-v));
    ob[i] = f2bf(o[i]);
  }
  *(float4*)(uc + (size_t)m * DE + d4) = make_float4(o[0],o[1],o[2],o[3]);
  *(unsigned long long*)(uc_bf + (size_t)m * DE + d4) = *(const unsigned long long*)ob;
}

// ---------------------------------------------------------------------------
// delta[M,2048] = softplus(dt[M,64] @ W_dt[2048,64]^T + b_dt). Single K pass.
// ---------------------------------------------------------------------------
__global__ __launch_bounds__(256)
void delta_k(const float* __restrict__ proj, const float* __restrict__ Wdt,
             const float* __restrict__ bdt, float* __restrict__ dl) {
  __shared__ float As[64][64];
  __shared__ float Bs[64][64];
  const int tid = threadIdx.x;
  const int row0 = blockIdx.y * 64, col0 = blockIdx.x * 64;
  const int ty = tid >> 4, tx = tid & 15;
  #pragma unroll
  for (int q = 0; q < 4; ++q) {
    const int f = q*256 + tid;
    const int rr = f >> 4, cc = (f & 15) << 2;
    float4 v = *(const float4*)(proj + (size_t)(row0+rr)*96 + 32 + cc);
    As[cc+0][rr]=v.x; As[cc+1][rr]=v.y; As[cc+2][rr]=v.z; As[cc+3][rr]=v.w;
    float4 w = *(const float4*)(Wdt + (size_t)(col0+rr)*64 + cc);
    Bs[cc+0][rr]=w.x; Bs[cc+1][rr]=w.y; Bs[cc+2][rr]=w.z; Bs[cc+3][rr]=w.w;
  }
  __syncthreads();
  float acc[4][4];
  #pragma unroll
  for (int i = 0; i < 4; ++i)
    #pragma unroll
    for (int j = 0; j < 4; ++j) acc[i][j] = 0.f;
  #pragma unroll 8
  for (int k = 0; k < 64; ++k) {
    const float4 a = *(const float4*)&As[k][ty*4];
    const float4 w = *(const float4*)&Bs[k][tx*4];
    const float a_[4]={a.x,a.y,a.z,a.w}, b_[4]={w.x,w.y,w.z,w.w};
    #pragma unroll
    for (int i = 0; i < 4; ++i)
      #pragma unroll
      for (int j = 0; j < 4; ++j)
        acc[i][j] = fmaf(a_[i], b_[j], acc[i][j]);
  }
  #pragma unroll
  for (int i = 0; i < 4; ++i) {
    const int m = row0 + ty*4 + i;
    #pragma unroll
    for (int j = 0; j < 4; ++j) {
      const int d = col0 + tx*4 + j;
      float v = acc[i][j] + bdt[d];
      float sp = (v > 20.f) ? v : log1pf(expf(v));
      dl[(size_t)m*DE + d] = sp;
    }
  }
}

// ---------------------------------------------------------------------------
// Chunked scan, phase 1: per (b, d, chunk) local scan from h=0.
// ---------------------------------------------------------------------------
__global__ __launch_bounds__(256)
void scan_part1(const float* __restrict__ dl, const float* __restrict__ uc,
                const float* __restrict__ proj, const float* __restrict__ Alog,
                float* __restrict__ hX, float* __restrict__ sumdv) {
  __shared__ float Bsh[CL][NS];
  const int tid = threadIdx.x;
  const int d = blockIdx.x * 256 + tid;
  const int c = blockIdx.y;
  const int b = blockIdx.z;
  const size_t mt0 = (size_t)b * L_ + c * CL;
  if (tid < CL * NS / 4) {
    const int t = tid >> 2, n4 = (tid & 3) * 4;
    float4 v = *(const float4*)(proj + (mt0 + t) * 96 + n4);
    Bsh[t][n4] = v.x; Bsh[t][n4+1] = v.y; Bsh[t][n4+2] = v.z; Bsh[t][n4+3] = v.w;
  }
  float An2[NS];
  #pragma unroll
  for (int q = 0; q < 4; ++q) {
    float4 a = *(const float4*)(Alog + d * NS + q * 4);
    An2[q*4+0] = -__expf(a.x) * 1.44269504f;
    An2[q*4+1] = -__expf(a.y) * 1.44269504f;
    An2[q*4+2] = -__expf(a.z) * 1.44269504f;
    An2[q*4+3] = -__expf(a.w) * 1.44269504f;
  }
  __syncthreads();
  float h[NS];
  #pragma unroll
  for (int n = 0; n < NS; ++n) h[n] = 0.f;
  float sd = 0.f;
  size_t off = mt0 * DE + d;
  float dv = dl[off], uv = uc[off];
  for (int t = 0; t < CL; ++t) {
    float dvn = 0.f, uvn = 0.f;
    if (t + 1 < CL) { dvn = dl[off + DE]; uvn = uc[off + DE]; }
    sd += dv;
    const float du = dv * uv;
    #pragma unroll
    for (int n = 0; n < NS; ++n) {
      const float dA = exp2f(dv * An2[n]);
      h[n] = fmaf(dA, h[n], du * Bsh[t][n]);
    }
    dv = dvn; uv = uvn; off += DE;
  }
  const size_t xb = (size_t)(b * NC + c) * NS * DE + d;
  #pragma unroll
  for (int n = 0; n < NS; ++n) hX[xb + (size_t)n * DE] = h[n];
  sumdv[(size_t)(b * NC + c) * DE + d] = sd;
}

// ---------------------------------------------------------------------------
// Chunked scan, phase 2: sequential combine over chunks (in place).
// ---------------------------------------------------------------------------
__global__ __launch_bounds__(256)
void scan_combine(float* __restrict__ hX, const float* __restrict__ sumdv,
                  const float* __restrict__ Alog) {
  const int tid = threadIdx.x;
  const int d = blockIdx.x * 256 + tid;
  const int n = blockIdx.y;
  const int b = blockIdx.z;
  const float An2 = -__expf(Alog[d * NS + n]) * 1.44269504f;
  float H = 0.f;
  for (int c = 0; c < NC; ++c) {
    const size_t xi = ((size_t)(b * NC + c) * NS + n) * DE + d;
    const float hf = hX[xi];
    const float sd = sumdv[(size_t)(b * NC + c) * DE + d];
    hX[xi] = H;
    H = fmaf(exp2f(sd * An2), H, hf);
  }
}

// ---------------------------------------------------------------------------
// Chunked scan, phase 3: re-run chunk from true start, fused epilogue
// (y + u*D) * silu(z) written as bf16 into ybf[M, DE].
// ---------------------------------------------------------------------------
__global__ __launch_bounds__(256)
void scan_part2(const float* __restrict__ dl, const float* __restrict__ uc,
                const float* __restrict__ proj, const float* __restrict__ hX,
                const float* __restrict__ Alog, const float* __restrict__ Dv,
                const float* __restrict__ xz, unsigned short* __restrict__ ybf) {
  __shared__ float Bsh[CL][NS];
  __shared__ float Csh[CL][NS];
  const int tid = threadIdx.x;
  const int d = blockIdx.x * 256 + tid;
  const int c = blockIdx.y;
  const int b = blockIdx.z;
  const size_t mt0 = (size_t)b * L_ + c * CL;
  if (tid < 128) {
    const int t = tid >> 2, n4 = (tid & 3) * 4;
    float4 v = *(const float4*)(proj + (mt0 + t) * 96 + n4);
    Bsh[t][n4] = v.x; Bsh[t][n4+1] = v.y; Bsh[t][n4+2] = v.z; Bsh[t][n4+3] = v.w;
  } else {
    const int u = tid - 128;
    const int t = u >> 2, n4 = (u & 3) * 4;
    float4 v = *(const float4*)(proj + (mt0 + t) * 96 + 16 + n4);
    Csh[t][n4] = v.x; Csh[t][n4+1] = v.y; Csh[t][n4+2] = v.z; Csh[t][n4+3] = v.w;
  }
  float An2[NS];
  #pragma unroll
  for (int q = 0; q < 4; ++q) {
    float4 a = *(const float4*)(Alog + d * NS + q * 4);
    An2[q*4+0] = -__expf(a.x) * 1.44269504f;
    An2[q*4+1] = -__expf(a.y) * 1.44269504f;
    An2[q*4+2] = -__expf(a.z) * 1.44269504f;
    An2[q*4+3] = -__expf(a.w) * 1.44269504f;
  }
  const float Dd = Dv[d];
  float h[NS];
  const size_t xb = (size_t)(b * NC + c) * NS * DE + d;
  #pragma unroll
  for (int n = 0; n < NS; ++n) h[n] = hX[xb + (size_t)n * DE];
  __syncthreads();
  size_t off = mt0 * DE + d;
  size_t zoff = mt0 * 4096 + d;
  float dv = dl[off], uv = uc[off];
  for (int t = 0; t < CL; ++t) {
    float dvn = 0.f, uvn = 0.f;
    if (t + 1 < CL) { dvn = dl[off + DE]; uvn = uc[off + DE]; }
    const float zv = xz[zoff + 2048];
    const float du = dv * uv;
    float y = 0.f;
    #pragma unroll
    for (int n = 0; n < NS; ++n) {
      const float dA = exp2f(dv * An2[n]);
      h[n] = fmaf(dA, h[n], du * Bsh[t][n]);
      y = fmaf(h[n], Csh[t][n], y);
    }
    y = fmaf(uv, Dd, y);
    const float sz = zv / (1.f + __expf(-zv));
    ybf[off] = f2bf(y * sz);
    dv = dvn; uv = uvn; off += DE; zoff += 4096;
  }
}

// ---------------------------------------------------------------------------
extern "C" void kernel_launch(void* const* d_in, const int* in_sizes, int n_in,
                              void* d_out, int out_size, void* d_ws, size_t ws_size,
                              hipStream_t stream) {
  const float* x    = (const float*)d_in[0];
  const float* Win  = (const float*)d_in[1];
  const float* cw   = (const float*)d_in[2];
  const float* cb   = (const float*)d_in[3];
  const float* Wx   = (const float*)d_in[4];
  const float* Wdt  = (const float*)d_in[5];
  const float* bdt  = (const float*)d_in[6];
  const float* Alog = (const float*)d_in[7];
  const float* Dv   = (const float*)d_in[8];
  const float* Wout = (const float*)d_in[9];
  float* out = (float*)d_out;
  float* ws  = (float*)d_ws;

  float*          xz    = ws;                    // 16777216 f32 (u | z)
  float*          uc    = ws + 16777216;         //  8388608 f32
  float*          proj  = ws + 25165824;         //   393216 f32
  float*          dl    = ws + 25559040;         //  8388608 f32
  float*          hX    = ws + 33947648;         //  4194304 f32 [b][c][n][d]
  float*          sumdv = ws + 38141952;         //   262144 f32
  // partial aliases hX+sumdv region (needed only BEFORE scan): 8*4096*128 f32
  float*          part  = ws + 33947648;         //  4194304 f32
  unsigned short* x_bf    = (unsigned short*)(ws + 38404096); // 4M bf16
  unsigned short* Win_bf  = (unsigned short*)(ws + 40501248); // 4M bf16
  unsigned short* Wout_bf = (unsigned short*)(ws + 42598400); // 2M bf16
  // y_bf aliases uc_bf (uc_bf consumed by proj_gemm before scan_part2 writes y)
  unsigned short* uc_bf   = (unsigned short*)(ws + 43646976); // 8M bf16
  unsigned short* y_bf    = uc_bf;
  unsigned short* Wxp_bf  = (unsigned short*)(ws + 47841280); // 256K bf16

  // 0) weight/input conversion to bf16
  f2bf_k<<<2048, 256, 0, stream>>>(x,   x_bf);
  f2bf_k<<<2048, 256, 0, stream>>>(Win, Win_bf);
  f2bf_k<<<1024, 256, 0, stream>>>(Wout, Wout_bf);
  wxpad_k<<<128, 256, 0, stream>>>(Wx, Wxp_bf);
  // 1) xz = x @ W_in^T  (bf16 MFMA)
  gemm_bf16_abt<<<dim3(32, 32), 256, 0, stream>>>(x_bf, DM, Win_bf, DM, xz, 4096, DM);
  // 2) uc = silu(depthwise_conv3(u) + conv_b)  (+ bf16 copy)
  conv_silu_k<<<8192, 256, 0, stream>>>(xz, cw, cb, uc, uc_bf);
  // 3) proj = uc @ W_xproj^T  (bf16 MFMA, split-K=8 + reduce)
  proj_gemm_k<<<dim3(8, 32), 256, 0, stream>>>(uc_bf, Wxp_bf, part);
  proj_reduce_k<<<384, 256, 0, stream>>>(part, proj);
  // 4) delta = softplus(dt @ W_dt^T + b_dt)
  delta_k<<<dim3(32, 64), 256, 0, stream>>>(proj, Wdt, bdt, dl);
  // 5) chunked selective scan -> y_bf
  scan_part1<<<dim3(DE/256, NC, B_), 256, 0, stream>>>(dl, uc, proj, Alog, hX, sumdv);
  scan_combine<<<dim3(DE/256, NS, B_), 256, 0, stream>>>(hX, sumdv, Alog);
  scan_part2<<<dim3(DE/256, NC, B_), 256, 0, stream>>>(dl, uc, proj, hX, Alog, Dv, xz, y_bf);
  // 6) out = y @ W_out^T  (bf16 MFMA)
  gemm_bf16_abt<<<dim3(8, 32), 256, 0, stream>>>(y_bf, DE, Wout_bf, DE, out, DM, DE);
}

// Round 5
// 261.943 us; speedup vs baseline: 6.5155x; 1.1182x over previous
//
#include <hip/hip_runtime.h>
#include <math.h>

#define B_   4
#define L_   1024
#define DM   1024
#define DE   2048
#define NS   16
#define M_   (B_*L_)   // 4096
#define NC   32        // scan chunks
#define CL   32        // chunk length (NC*CL == L_)

typedef __attribute__((ext_vector_type(8))) short bf16x8;
typedef __attribute__((ext_vector_type(4))) float f32x4;

#define AS1 __attribute__((address_space(1)))
#define AS3 __attribute__((address_space(3)))

__device__ __forceinline__ void gload_lds16(const void* g, void* l) {
  __builtin_amdgcn_global_load_lds((const AS1 unsigned int*)g,
                                   (AS3 unsigned int*)l, 16, 0, 0);
}

__device__ __forceinline__ unsigned short f2bf(float f) {
  unsigned int u = __builtin_bit_cast(unsigned int, f);
  u = (u + 0x7fffu + ((u >> 16) & 1u)) >> 16;   // round-to-nearest-even
  return (unsigned short)u;
}
__device__ __forceinline__ float bf2f(unsigned short h) {
  unsigned int u = ((unsigned int)h) << 16;
  return __builtin_bit_cast(float, u);
}

// ---------------------------------------------------------------------------
// Merged f32->bf16 converts: x (2048 blk), Win (2048), Wout (1024), Wxp (128)
// Each block: 2048 elements (256 thr x 8).
// ---------------------------------------------------------------------------
__global__ __launch_bounds__(256)
void convert_all_k(const float* __restrict__ x, const float* __restrict__ Win,
                   const float* __restrict__ Wout, const float* __restrict__ Wx,
                   unsigned short* __restrict__ x_bf, unsigned short* __restrict__ Win_bf,
                   unsigned short* __restrict__ Wout_bf, unsigned short* __restrict__ Wxp) {
  const int blk = blockIdx.x;
  const float* src; unsigned short* dst; size_t base; bool pad = false; int prow = 0;
  if (blk < 2048)      { src = x;    dst = x_bf;    base = (size_t)blk * 2048; }
  else if (blk < 4096) { src = Win;  dst = Win_bf;  base = (size_t)(blk - 2048) * 2048; }
  else if (blk < 5120) { src = Wout; dst = Wout_bf; base = (size_t)(blk - 4096) * 2048; }
  else                 { src = Wx;   dst = Wxp;     base = (size_t)(blk - 5120) * 2048; pad = true; }
  const size_t i = base + (size_t)threadIdx.x * 8;
  unsigned short o[8] = {0,0,0,0,0,0,0,0};
  if (!pad || (int)(i >> 11) < 96) {
    float4 a = *(const float4*)(src + i);
    float4 b = *(const float4*)(src + i + 4);
    o[0]=f2bf(a.x); o[1]=f2bf(a.y); o[2]=f2bf(a.z); o[3]=f2bf(a.w);
    o[4]=f2bf(b.x); o[5]=f2bf(b.y); o[6]=f2bf(b.z); o[7]=f2bf(b.w);
  }
  *(ulonglong2*)(dst + i) = *(const ulonglong2*)o;
}

// ---------------------------------------------------------------------------
// bf16 MFMA GEMM (m97 structure): C[M,N]f32 = A[M,K]bf16 @ Bt[N,K]bf16^T.
// 128x128 tile, BK=32, 256 threads (4 waves, 2x2 of 64x64), global_load_lds.
// ---------------------------------------------------------------------------
__global__ __launch_bounds__(256)
void gemm_bf16_abt(const unsigned short* __restrict__ A, int lda,
                   const unsigned short* __restrict__ Bt, int ldb,
                   float* __restrict__ C, int ldc, int K) {
  __shared__ unsigned short Asl[128 * 32];
  __shared__ unsigned short Bsl[128 * 32];
  const int tid  = threadIdx.x;
  const int lane = tid & 63;
  const int wave = tid >> 6;
  const int row0 = blockIdx.y * 128, col0 = blockIdx.x * 128;
  const int wr = (wave >> 1) * 64, wc = (wave & 1) * 64;

  const int c0 = tid, c1 = 256 + tid;
  const unsigned short* Ag0 = A + (size_t)(row0 + (c0 >> 2)) * lda + ((c0 & 3) << 3);
  const unsigned short* Ag1 = A + (size_t)(row0 + (c1 >> 2)) * lda + ((c1 & 3) << 3);
  const unsigned short* Bg0 = Bt + (size_t)(col0 + (c0 >> 2)) * ldb + ((c0 & 3) << 3);
  const unsigned short* Bg1 = Bt + (size_t)(col0 + (c1 >> 2)) * ldb + ((c1 & 3) << 3);
  unsigned short* Al0 = Asl + ((wave << 6) << 3);
  unsigned short* Al1 = Asl + ((256 + (wave << 6)) << 3);
  unsigned short* Bl0 = Bsl + ((wave << 6) << 3);
  unsigned short* Bl1 = Bsl + ((256 + (wave << 6)) << 3);

  const int frow = lane & 15;
  const int fk   = (lane >> 4) << 3;
  const unsigned short* Afr = Asl + ((wr + frow) << 5) + fk;
  const unsigned short* Bfr = Bsl + ((wc + frow) << 5) + fk;

  f32x4 acc[4][4];
  #pragma unroll
  for (int m = 0; m < 4; ++m)
    #pragma unroll
    for (int n = 0; n < 4; ++n) acc[m][n] = (f32x4){0.f, 0.f, 0.f, 0.f};

  for (int k0 = 0; k0 < K; k0 += 32) {
    __syncthreads();
    gload_lds16(Ag0 + k0, Al0);
    gload_lds16(Ag1 + k0, Al1);
    gload_lds16(Bg0 + k0, Bl0);
    gload_lds16(Bg1 + k0, Bl1);
    __syncthreads();
    bf16x8 af[4], bfr[4];
    #pragma unroll
    for (int m = 0; m < 4; ++m) af[m]  = *(const bf16x8*)(Afr + (m << 9));
    #pragma unroll
    for (int n = 0; n < 4; ++n) bfr[n] = *(const bf16x8*)(Bfr + (n << 9));
    #pragma unroll
    for (int m = 0; m < 4; ++m)
      #pragma unroll
      for (int n = 0; n < 4; ++n)
        acc[m][n] = __builtin_amdgcn_mfma_f32_16x16x32_bf16(af[m], bfr[n], acc[m][n], 0, 0, 0);
  }

  const int r4 = (lane >> 4) << 2;
  #pragma unroll
  for (int m = 0; m < 4; ++m)
    #pragma unroll
    for (int n = 0; n < 4; ++n) {
      float* Cp = C + (size_t)(row0 + wr + m * 16 + r4) * ldc + col0 + wc + n * 16 + (lane & 15);
      #pragma unroll
      for (int r = 0; r < 4; ++r) Cp[(size_t)r * ldc] = acc[m][n][r];
    }
}

// ---------------------------------------------------------------------------
// proj split-K MFMA: grid (ks=8, mtile=32). Each block: 128x128 tile over
// K range [ks*256, ks*256+256); writes f32 partial[ks][4096][128].
// ---------------------------------------------------------------------------
__global__ __launch_bounds__(256)
void proj_gemm_k(const unsigned short* __restrict__ A,      // uc_bf [4096][2048]
                 const unsigned short* __restrict__ Bt,     // Wxp   [128][2048]
                 float* __restrict__ part) {
  __shared__ unsigned short Asl[128 * 32];
  __shared__ unsigned short Bsl[128 * 32];
  const int tid  = threadIdx.x;
  const int lane = tid & 63;
  const int wave = tid >> 6;
  const int ks   = blockIdx.x;
  const int row0 = blockIdx.y * 128;
  const int wr = (wave >> 1) * 64, wc = (wave & 1) * 64;
  const int kbase = ks * 256;

  const int c0 = tid, c1 = 256 + tid;
  const unsigned short* Ag0 = A + (size_t)(row0 + (c0 >> 2)) * DE + ((c0 & 3) << 3) + kbase;
  const unsigned short* Ag1 = A + (size_t)(row0 + (c1 >> 2)) * DE + ((c1 & 3) << 3) + kbase;
  const unsigned short* Bg0 = Bt + (size_t)(c0 >> 2) * DE + ((c0 & 3) << 3) + kbase;
  const unsigned short* Bg1 = Bt + (size_t)(c1 >> 2) * DE + ((c1 & 3) << 3) + kbase;
  unsigned short* Al0 = Asl + ((wave << 6) << 3);
  unsigned short* Al1 = Asl + ((256 + (wave << 6)) << 3);
  unsigned short* Bl0 = Bsl + ((wave << 6) << 3);
  unsigned short* Bl1 = Bsl + ((256 + (wave << 6)) << 3);

  const int frow = lane & 15;
  const int fk   = (lane >> 4) << 3;
  const unsigned short* Afr = Asl + ((wr + frow) << 5) + fk;
  const unsigned short* Bfr = Bsl + ((wc + frow) << 5) + fk;

  f32x4 acc[4][4];
  #pragma unroll
  for (int m = 0; m < 4; ++m)
    #pragma unroll
    for (int n = 0; n < 4; ++n) acc[m][n] = (f32x4){0.f, 0.f, 0.f, 0.f};

  for (int k0 = 0; k0 < 256; k0 += 32) {
    __syncthreads();
    gload_lds16(Ag0 + k0, Al0);
    gload_lds16(Ag1 + k0, Al1);
    gload_lds16(Bg0 + k0, Bl0);
    gload_lds16(Bg1 + k0, Bl1);
    __syncthreads();
    bf16x8 af[4], bfr[4];
    #pragma unroll
    for (int m = 0; m < 4; ++m) af[m]  = *(const bf16x8*)(Afr + (m << 9));
    #pragma unroll
    for (int n = 0; n < 4; ++n) bfr[n] = *(const bf16x8*)(Bfr + (n << 9));
    #pragma unroll
    for (int m = 0; m < 4; ++m)
      #pragma unroll
      for (int n = 0; n < 4; ++n)
        acc[m][n] = __builtin_amdgcn_mfma_f32_16x16x32_bf16(af[m], bfr[n], acc[m][n], 0, 0, 0);
  }

  float* Cb = part + (size_t)ks * (M_ * 128) + (size_t)row0 * 128;
  const int r4 = (lane >> 4) << 2;
  #pragma unroll
  for (int m = 0; m < 4; ++m)
    #pragma unroll
    for (int n = 0; n < 4; ++n) {
      float* Cp = Cb + (size_t)(wr + m * 16 + r4) * 128 + wc + n * 16 + (lane & 15);
      #pragma unroll
      for (int r = 0; r < 4; ++r) Cp[(size_t)r * 128] = acc[m][n][r];
    }
}

// ---------------------------------------------------------------------------
// proj reduce: proj[m][j] = sum_ks part[ks][m][j], j in [0,96)
// ---------------------------------------------------------------------------
__global__ __launch_bounds__(256)
void proj_reduce_k(const float* __restrict__ part, float* __restrict__ proj) {
  const int g = blockIdx.x * 256 + threadIdx.x;   // [0, 4096*24)
  const int m = g / 24;
  const int j4 = (g - m * 24) * 4;
  float4 s = make_float4(0.f, 0.f, 0.f, 0.f);
  #pragma unroll
  for (int ks = 0; ks < 8; ++ks) {
    float4 v = *(const float4*)(part + (size_t)ks * (M_ * 128) + (size_t)m * 128 + j4);
    s.x += v.x; s.y += v.y; s.z += v.z; s.w += v.w;
  }
  *(float4*)(proj + (size_t)m * 96 + j4) = s;
}

// ---------------------------------------------------------------------------
// Depthwise conv(k=3, pad 1) + bias + SiLU. Writes bf16 uc only.
// ---------------------------------------------------------------------------
__global__ __launch_bounds__(256)
void conv_silu_k(const float* __restrict__ xz, const float* __restrict__ cw,
                 const float* __restrict__ cb, unsigned short* __restrict__ uc_bf) {
  const int g = blockIdx.x * 256 + threadIdx.x;   // [0, M_*DE/4)
  const int m = g >> 9;
  const int d4 = (g & 511) << 2;
  const int l = m & (L_ - 1);
  const float* row = xz + (size_t)m * 4096 + d4;
  float4 cur = *(const float4*)row;
  float4 prv = make_float4(0.f,0.f,0.f,0.f);
  float4 nxt = make_float4(0.f,0.f,0.f,0.f);
  if (l > 0)      prv = *(const float4*)(row - 4096);
  if (l < L_ - 1) nxt = *(const float4*)(row + 4096);
  const float pc[4] = {prv.x,prv.y,prv.z,prv.w};
  const float cc[4] = {cur.x,cur.y,cur.z,cur.w};
  const float nc[4] = {nxt.x,nxt.y,nxt.z,nxt.w};
  unsigned short ob[4];
  #pragma unroll
  for (int i = 0; i < 4; ++i) {
    const int d = d4 + i;
    float v = cb[d] + cw[d*3]*pc[i] + cw[d*3+1]*cc[i] + cw[d*3+2]*nc[i];
    ob[i] = f2bf(v / (1.f + __expf(-v)));
  }
  *(unsigned long long*)(uc_bf + (size_t)m * DE + d4) = *(const unsigned long long*)ob;
}

// ---------------------------------------------------------------------------
// delta[M,2048] = softplus(dt[M,64] @ W_dt[2048,64]^T + b_dt). Fast softplus.
// ---------------------------------------------------------------------------
__global__ __launch_bounds__(256)
void delta_k(const float* __restrict__ proj, const float* __restrict__ Wdt,
             const float* __restrict__ bdt, float* __restrict__ dl) {
  __shared__ float As[64][64];
  __shared__ float Bs[64][64];
  const int tid = threadIdx.x;
  const int row0 = blockIdx.y * 64, col0 = blockIdx.x * 64;
  const int ty = tid >> 4, tx = tid & 15;
  #pragma unroll
  for (int q = 0; q < 4; ++q) {
    const int f = q*256 + tid;
    const int rr = f >> 4, cc = (f & 15) << 2;
    float4 v = *(const float4*)(proj + (size_t)(row0+rr)*96 + 32 + cc);
    As[cc+0][rr]=v.x; As[cc+1][rr]=v.y; As[cc+2][rr]=v.z; As[cc+3][rr]=v.w;
    float4 w = *(const float4*)(Wdt + (size_t)(col0+rr)*64 + cc);
    Bs[cc+0][rr]=w.x; Bs[cc+1][rr]=w.y; Bs[cc+2][rr]=w.z; Bs[cc+3][rr]=w.w;
  }
  __syncthreads();
  float acc[4][4];
  #pragma unroll
  for (int i = 0; i < 4; ++i)
    #pragma unroll
    for (int j = 0; j < 4; ++j) acc[i][j] = 0.f;
  #pragma unroll 8
  for (int k = 0; k < 64; ++k) {
    const float4 a = *(const float4*)&As[k][ty*4];
    const float4 w = *(const float4*)&Bs[k][tx*4];
    const float a_[4]={a.x,a.y,a.z,a.w}, b_[4]={w.x,w.y,w.z,w.w};
    #pragma unroll
    for (int i = 0; i < 4; ++i)
      #pragma unroll
      for (int j = 0; j < 4; ++j)
        acc[i][j] = fmaf(a_[i], b_[j], acc[i][j]);
  }
  #pragma unroll
  for (int i = 0; i < 4; ++i) {
    const int m = row0 + ty*4 + i;
    #pragma unroll
    for (int j = 0; j < 4; ++j) {
      const int d = col0 + tx*4 + j;
      float v = acc[i][j] + bdt[d];
      // softplus(v) = max(v,0) + log1p(exp(-|v|)) with fast intrinsics
      float sp = fmaxf(v, 0.f) + __logf(1.f + __expf(-fabsf(v)));
      dl[(size_t)m*DE + d] = sp;
    }
  }
}

// ---------------------------------------------------------------------------
// Chunked scan, phase 1: per (b, d, chunk) local scan from h=0. uc in bf16.
// ---------------------------------------------------------------------------
__global__ __launch_bounds__(256)
void scan_part1(const float* __restrict__ dl, const unsigned short* __restrict__ uc,
                const float* __restrict__ proj, const float* __restrict__ Alog,
                float* __restrict__ hX, float* __restrict__ sumdv) {
  __shared__ float Bsh[CL][NS];
  const int tid = threadIdx.x;
  const int d = blockIdx.x * 256 + tid;
  const int c = blockIdx.y;
  const int b = blockIdx.z;
  const size_t mt0 = (size_t)b * L_ + c * CL;
  if (tid < CL * NS / 4) {
    const int t = tid >> 2, n4 = (tid & 3) * 4;
    float4 v = *(const float4*)(proj + (mt0 + t) * 96 + n4);
    Bsh[t][n4] = v.x; Bsh[t][n4+1] = v.y; Bsh[t][n4+2] = v.z; Bsh[t][n4+3] = v.w;
  }
  float An2[NS];
  #pragma unroll
  for (int q = 0; q < 4; ++q) {
    float4 a = *(const float4*)(Alog + d * NS + q * 4);
    An2[q*4+0] = -__expf(a.x) * 1.44269504f;
    An2[q*4+1] = -__expf(a.y) * 1.44269504f;
    An2[q*4+2] = -__expf(a.z) * 1.44269504f;
    An2[q*4+3] = -__expf(a.w) * 1.44269504f;
  }
  __syncthreads();
  float h[NS];
  #pragma unroll
  for (int n = 0; n < NS; ++n) h[n] = 0.f;
  float sd = 0.f;
  size_t off = mt0 * DE + d;
  float dv = dl[off], uv = bf2f(uc[off]);
  for (int t = 0; t < CL; ++t) {
    float dvn = 0.f, uvn = 0.f;
    if (t + 1 < CL) { dvn = dl[off + DE]; uvn = bf2f(uc[off + DE]); }
    sd += dv;
    const float du = dv * uv;
    #pragma unroll
    for (int n = 0; n < NS; ++n) {
      const float dA = exp2f(dv * An2[n]);
      h[n] = fmaf(dA, h[n], du * Bsh[t][n]);
    }
    dv = dvn; uv = uvn; off += DE;
  }
  const size_t xb = (size_t)(b * NC + c) * NS * DE + d;
  #pragma unroll
  for (int n = 0; n < NS; ++n) hX[xb + (size_t)n * DE] = h[n];
  sumdv[(size_t)(b * NC + c) * DE + d] = sd;
}

// ---------------------------------------------------------------------------
// Chunked scan, phase 2: sequential combine over chunks (in place).
// ---------------------------------------------------------------------------
__global__ __launch_bounds__(256)
void scan_combine(float* __restrict__ hX, const float* __restrict__ sumdv,
                  const float* __restrict__ Alog) {
  const int tid = threadIdx.x;
  const int d = blockIdx.x * 256 + tid;
  const int n = blockIdx.y;
  const int b = blockIdx.z;
  const float An2 = -__expf(Alog[d * NS + n]) * 1.44269504f;
  float H = 0.f;
  for (int c = 0; c < NC; ++c) {
    const size_t xi = ((size_t)(b * NC + c) * NS + n) * DE + d;
    const float hf = hX[xi];
    const float sd = sumdv[(size_t)(b * NC + c) * DE + d];
    hX[xi] = H;
    H = fmaf(exp2f(sd * An2), H, hf);
  }
}

// ---------------------------------------------------------------------------
// Chunked scan, phase 3: re-run chunk from true start, fused epilogue
// (y + u*D) * silu(z) written as bf16 into ybf (aliases uc: in-place safe,
// each column owned by one thread and t+1 prefetch precedes the t write).
// ---------------------------------------------------------------------------
__global__ __launch_bounds__(256)
void scan_part2(const float* __restrict__ dl, const unsigned short* __restrict__ uc,
                const float* __restrict__ proj, const float* __restrict__ hX,
                const float* __restrict__ Alog, const float* __restrict__ Dv,
                const float* __restrict__ xz, unsigned short* __restrict__ ybf) {
  __shared__ float Bsh[CL][NS];
  __shared__ float Csh[CL][NS];
  const int tid = threadIdx.x;
  const int d = blockIdx.x * 256 + tid;
  const int c = blockIdx.y;
  const int b = blockIdx.z;
  const size_t mt0 = (size_t)b * L_ + c * CL;
  if (tid < 128) {
    const int t = tid >> 2, n4 = (tid & 3) * 4;
    float4 v = *(const float4*)(proj + (mt0 + t) * 96 + n4);
    Bsh[t][n4] = v.x; Bsh[t][n4+1] = v.y; Bsh[t][n4+2] = v.z; Bsh[t][n4+3] = v.w;
  } else {
    const int u = tid - 128;
    const int t = u >> 2, n4 = (u & 3) * 4;
    float4 v = *(const float4*)(proj + (mt0 + t) * 96 + 16 + n4);
    Csh[t][n4] = v.x; Csh[t][n4+1] = v.y; Csh[t][n4+2] = v.z; Csh[t][n4+3] = v.w;
  }
  float An2[NS];
  #pragma unroll
  for (int q = 0; q < 4; ++q) {
    float4 a = *(const float4*)(Alog + d * NS + q * 4);
    An2[q*4+0] = -__expf(a.x) * 1.44269504f;
    An2[q*4+1] = -__expf(a.y) * 1.44269504f;
    An2[q*4+2] = -__expf(a.z) * 1.44269504f;
    An2[q*4+3] = -__expf(a.w) * 1.44269504f;
  }
  const float Dd = Dv[d];
  float h[NS];
  const size_t xb = (size_t)(b * NC + c) * NS * DE + d;
  #pragma unroll
  for (int n = 0; n < NS; ++n) h[n] = hX[xb + (size_t)n * DE];
  __syncthreads();
  size_t off = mt0 * DE + d;
  size_t zoff = mt0 * 4096 + d;
  float dv = dl[off], uv = bf2f(uc[off]);
  for (int t = 0; t < CL; ++t) {
    float dvn = 0.f, uvn = 0.f;
    if (t + 1 < CL) { dvn = dl[off + DE]; uvn = bf2f(uc[off + DE]); }
    const float zv = xz[zoff + 2048];
    const float du = dv * uv;
    float y = 0.f;
    #pragma unroll
    for (int n = 0; n < NS; ++n) {
      const float dA = exp2f(dv * An2[n]);
      h[n] = fmaf(dA, h[n], du * Bsh[t][n]);
      y = fmaf(h[n], Csh[t][n], y);
    }
    y = fmaf(uv, Dd, y);
    const float sz = zv / (1.f + __expf(-zv));
    ybf[off] = f2bf(y * sz);
    dv = dvn; uv = uvn; off += DE; zoff += 4096;
  }
}

// ---------------------------------------------------------------------------
extern "C" void kernel_launch(void* const* d_in, const int* in_sizes, int n_in,
                              void* d_out, int out_size, void* d_ws, size_t ws_size,
                              hipStream_t stream) {
  const float* x    = (const float*)d_in[0];
  const float* Win  = (const float*)d_in[1];
  const float* cw   = (const float*)d_in[2];
  const float* cb   = (const float*)d_in[3];
  const float* Wx   = (const float*)d_in[4];
  const float* Wdt  = (const float*)d_in[5];
  const float* bdt  = (const float*)d_in[6];
  const float* Alog = (const float*)d_in[7];
  const float* Dv   = (const float*)d_in[8];
  const float* Wout = (const float*)d_in[9];
  float* out = (float*)d_out;
  float* ws  = (float*)d_ws;

  float*          xz    = ws;                    // 16777216 f32 (u | z)
  float*          proj  = ws + 25165824;         //   393216 f32
  float*          dl    = ws + 25559040;         //  8388608 f32
  float*          hX    = ws + 33947648;         //  4194304 f32 [b][c][n][d]
  float*          sumdv = ws + 38141952;         //   262144 f32
  float*          part  = ws + 33947648;         //  aliases hX (pre-scan only)
  unsigned short* x_bf    = (unsigned short*)(ws + 38404096); // 4M bf16
  unsigned short* Win_bf  = (unsigned short*)(ws + 40501248); // 4M bf16
  unsigned short* Wout_bf = (unsigned short*)(ws + 42598400); // 2M bf16
  unsigned short* uc_bf   = (unsigned short*)(ws + 43646976); // 8M bf16
  unsigned short* y_bf    = uc_bf;               // in-place y over uc
  unsigned short* Wxp_bf  = (unsigned short*)(ws + 47841280); // 256K bf16

  // 0) all f32->bf16 conversions in one kernel
  convert_all_k<<<5248, 256, 0, stream>>>(x, Win, Wout, Wx, x_bf, Win_bf, Wout_bf, Wxp_bf);
  // 1) xz = x @ W_in^T  (bf16 MFMA)
  gemm_bf16_abt<<<dim3(32, 32), 256, 0, stream>>>(x_bf, DM, Win_bf, DM, xz, 4096, DM);
  // 2) uc = silu(depthwise_conv3(u) + conv_b)  -> bf16
  conv_silu_k<<<8192, 256, 0, stream>>>(xz, cw, cb, uc_bf);
  // 3) proj = uc @ W_xproj^T  (bf16 MFMA, split-K=8 + reduce)
  proj_gemm_k<<<dim3(8, 32), 256, 0, stream>>>(uc_bf, Wxp_bf, part);
  proj_reduce_k<<<384, 256, 0, stream>>>(part, proj);
  // 4) delta = softplus(dt @ W_dt^T + b_dt)
  delta_k<<<dim3(32, 64), 256, 0, stream>>>(proj, Wdt, bdt, dl);
  // 5) chunked selective scan -> y_bf (in place over uc_bf)
  scan_part1<<<dim3(DE/256, NC, B_), 256, 0, stream>>>(dl, uc_bf, proj, Alog, hX, sumdv);
  scan_combine<<<dim3(DE/256, NS, B_), 256, 0, stream>>>(hX, sumdv, Alog);
  scan_part2<<<dim3(DE/256, NC, B_), 256, 0, stream>>>(dl, uc_bf, proj, hX, Alog, Dv, xz, y_bf);
  // 6) out = y @ W_out^T  (bf16 MFMA)
  gemm_bf16_abt<<<dim3(8, 32), 256, 0, stream>>>(y_bf, DE, Wout_bf, DE, out, DM, DE);
}